// Round 1
// baseline (4883.220 us; speedup 1.0000x reference)
//
#include <hip/hip_runtime.h>
#include <hip/hip_bf16.h>

// Problem constants
#define Bsz 32
#define Esz 64
#define Ssz 50
#define Dsz 300
#define Fsz 100
#define Hsz 100
#define WWIN 5

__device__ __forceinline__ float sigmoidf_(float x) { return 1.0f / (1.0f + expf(-x)); }

// ---------------------------------------------------------------------------
// Kernel 1: per-(b,e) conv (window 5 over words, SAME pad) + relu,
//           attention pooling over words -> sent[b,e,F]
// grid = B*E blocks, 256 threads
// ---------------------------------------------------------------------------
__global__ __launch_bounds__(256) void conv_att1_kernel(
    const float* __restrict__ essays,    // [B,E,S,D]
    const float* __restrict__ conv_k,    // [1,5,D,F] (HWIO)
    const float* __restrict__ conv_b,    // [F]
    const float* __restrict__ att1_mat,  // [F,F]
    const float* __restrict__ att1_bias, // [F]
    const float* __restrict__ att1_vec,  // [F]
    float* __restrict__ sent)            // [B,E,F]
{
    __shared__ float conv_s[Ssz * Fsz];  // 5000 floats, 20 KB
    __shared__ float w1_s[Ssz * Fsz];    // 5000 floats, 20 KB
    __shared__ float red_s[Ssz];
    __shared__ float alpha_s[Ssz];

    const int be = blockIdx.x;
    const int tid = threadIdx.x;
    const float* in_g = essays + (size_t)be * (Ssz * Dsz);

    // ---- conv + bias + relu ----
    for (int idx = tid; idx < Ssz * Fsz; idx += 256) {
        const int s = idx / Fsz;
        const int f = idx % Fsz;
        float a0 = 0.f, a1 = 0.f, a2 = 0.f, a3 = 0.f;
#pragma unroll
        for (int w = 0; w < WWIN; ++w) {
            const int ss = s + w - 2;
            if (ss < 0 || ss >= Ssz) continue;
            const float4* ip = reinterpret_cast<const float4*>(in_g + ss * Dsz);
            const float* kp = conv_k + w * Dsz * Fsz + f;
            for (int d4 = 0; d4 < Dsz / 4; ++d4) {
                const float4 v = ip[d4];
                a0 += v.x * kp[(d4 * 4 + 0) * Fsz];
                a1 += v.y * kp[(d4 * 4 + 1) * Fsz];
                a2 += v.z * kp[(d4 * 4 + 2) * Fsz];
                a3 += v.w * kp[(d4 * 4 + 3) * Fsz];
            }
        }
        const float acc = conv_b[f] + ((a0 + a1) + (a2 + a3));
        conv_s[idx] = fmaxf(acc, 0.f);
    }
    __syncthreads();

    // ---- att1: w1[s][g] = tanh(sum_f conv[s][f]*mat[f][g] + bias[g]) * vec[g] ----
    for (int idx = tid; idx < Ssz * Fsz; idx += 256) {
        const int s = idx / Fsz;
        const int g = idx % Fsz;
        const float* cp = conv_s + s * Fsz;
        float a0 = 0.f, a1 = 0.f, a2 = 0.f, a3 = 0.f;
        for (int f4 = 0; f4 < Fsz; f4 += 4) {
            a0 += cp[f4 + 0] * att1_mat[(f4 + 0) * Fsz + g];
            a1 += cp[f4 + 1] * att1_mat[(f4 + 1) * Fsz + g];
            a2 += cp[f4 + 2] * att1_mat[(f4 + 2) * Fsz + g];
            a3 += cp[f4 + 3] * att1_mat[(f4 + 3) * Fsz + g];
        }
        const float t = tanhf(att1_bias[g] + ((a0 + a1) + (a2 + a3)));
        w1_s[idx] = t * att1_vec[g];
    }
    __syncthreads();

    // ---- u[s] = sum_g w1[s][g] ----
    for (int s = tid; s < Ssz; s += 256) {
        float acc = 0.f;
        const float* wp = w1_s + s * Fsz;
        for (int g = 0; g < Fsz; ++g) acc += wp[g];
        red_s[s] = acc;
    }
    __syncthreads();

    // ---- softmax over s (small: serial by thread 0) ----
    if (tid == 0) {
        float m = -1e30f;
        for (int s = 0; s < Ssz; ++s) m = fmaxf(m, red_s[s]);
        float sum = 0.f;
        for (int s = 0; s < Ssz; ++s) {
            const float e = expf(red_s[s] - m);
            alpha_s[s] = e;
            sum += e;
        }
        const float inv = 1.f / sum;
        for (int s = 0; s < Ssz; ++s) alpha_s[s] *= inv;
    }
    __syncthreads();

    // ---- sent[f] = sum_s alpha[s]*conv[s][f] ----
    for (int f = tid; f < Fsz; f += 256) {
        float acc = 0.f;
        for (int s = 0; s < Ssz; ++s) acc += alpha_s[s] * conv_s[s * Fsz + f];
        sent[(size_t)be * Fsz + f] = acc;
    }
}

// ---------------------------------------------------------------------------
// Kernel 2: LSTM over sentence axis (E sequential steps), one block per batch b
// grid = B blocks, 512 threads (400 active for gate matmul)
// ---------------------------------------------------------------------------
__global__ __launch_bounds__(512) void lstm_kernel(
    const float* __restrict__ sent,    // [B,E,F]
    const float* __restrict__ lstm_W,  // [F+H, 4H] row-major
    const float* __restrict__ lstm_b,  // [4H]
    float* __restrict__ lstm_out)      // [B,E,H]
{
    __shared__ float x_s[Fsz];
    __shared__ float h_s[Hsz];
    __shared__ float z_s[4 * Hsz];

    const int b = blockIdx.x;
    const int tid = threadIdx.x;
    float c = 0.f;
    if (tid < Hsz) h_s[tid] = 0.f;
    __syncthreads();

    for (int t = 0; t < Esz; ++t) {
        if (tid < Fsz) x_s[tid] = sent[((size_t)b * Esz + t) * Fsz + tid];
        __syncthreads();

        if (tid < 4 * Hsz) {
            const float* Wc = lstm_W + tid;  // column tid, stride 4H
            float a0 = lstm_b[tid], a1 = 0.f, a2 = 0.f, a3 = 0.f;
            for (int k = 0; k < Fsz; k += 4) {
                a0 += x_s[k + 0] * Wc[(k + 0) * 4 * Hsz];
                a1 += x_s[k + 1] * Wc[(k + 1) * 4 * Hsz];
                a2 += x_s[k + 2] * Wc[(k + 2) * 4 * Hsz];
                a3 += x_s[k + 3] * Wc[(k + 3) * 4 * Hsz];
            }
            for (int k = 0; k < Hsz; k += 4) {
                a0 += h_s[k + 0] * Wc[(Fsz + k + 0) * 4 * Hsz];
                a1 += h_s[k + 1] * Wc[(Fsz + k + 1) * 4 * Hsz];
                a2 += h_s[k + 2] * Wc[(Fsz + k + 2) * 4 * Hsz];
                a3 += h_s[k + 3] * Wc[(Fsz + k + 3) * 4 * Hsz];
            }
            z_s[tid] = (a0 + a1) + (a2 + a3);
        }
        __syncthreads();

        if (tid < Hsz) {
            const float zi = z_s[tid];
            const float zj = z_s[tid + Hsz];
            const float zf = z_s[tid + 2 * Hsz];
            const float zo = z_s[tid + 3 * Hsz];
            c = c * sigmoidf_(zf + 1.0f) + sigmoidf_(zi) * tanhf(zj);
            const float h = sigmoidf_(zo) * tanhf(c);
            h_s[tid] = h;
            lstm_out[((size_t)b * Esz + t) * Hsz + tid] = h;
        }
        __syncthreads();
    }
}

// ---------------------------------------------------------------------------
// Kernel 3: attention pooling over sentences + dense + sigmoid -> out[B]
// grid = B blocks, 256 threads
// ---------------------------------------------------------------------------
__global__ __launch_bounds__(256) void att2_kernel(
    const float* __restrict__ lstm,      // [B,E,H]
    const float* __restrict__ att2_mat,  // [H,H]
    const float* __restrict__ att2_bias, // [H]
    const float* __restrict__ att2_vec,  // [H]
    const float* __restrict__ dense_w,   // [H]
    const float* __restrict__ dense_b,   // [1]
    float* __restrict__ out)             // [B]
{
    __shared__ float l_s[Esz * Hsz];   // 6400 floats, 25.6 KB
    __shared__ float w2_s[Esz * Hsz];  // 25.6 KB
    __shared__ float u2_s[Esz];
    __shared__ float alpha_s[Esz];
    __shared__ float repr_s[Hsz];

    const int b = blockIdx.x;
    const int tid = threadIdx.x;

    for (int i = tid; i < Esz * Hsz; i += 256) l_s[i] = lstm[(size_t)b * Esz * Hsz + i];
    __syncthreads();

    for (int idx = tid; idx < Esz * Hsz; idx += 256) {
        const int e = idx / Hsz;
        const int g = idx % Hsz;
        const float* lp = l_s + e * Hsz;
        float a0 = 0.f, a1 = 0.f, a2 = 0.f, a3 = 0.f;
        for (int h4 = 0; h4 < Hsz; h4 += 4) {
            a0 += lp[h4 + 0] * att2_mat[(h4 + 0) * Hsz + g];
            a1 += lp[h4 + 1] * att2_mat[(h4 + 1) * Hsz + g];
            a2 += lp[h4 + 2] * att2_mat[(h4 + 2) * Hsz + g];
            a3 += lp[h4 + 3] * att2_mat[(h4 + 3) * Hsz + g];
        }
        const float t = tanhf(att2_bias[g] + ((a0 + a1) + (a2 + a3)));
        w2_s[idx] = t * att2_vec[g];
    }
    __syncthreads();

    for (int e = tid; e < Esz; e += 256) {
        float acc = 0.f;
        const float* wp = w2_s + e * Hsz;
        for (int g = 0; g < Hsz; ++g) acc += wp[g];
        u2_s[e] = acc;
    }
    __syncthreads();

    if (tid == 0) {
        float m = -1e30f;
        for (int e = 0; e < Esz; ++e) m = fmaxf(m, u2_s[e]);
        float sum = 0.f;
        for (int e = 0; e < Esz; ++e) {
            const float ex = expf(u2_s[e] - m);
            alpha_s[e] = ex;
            sum += ex;
        }
        const float inv = 1.f / sum;
        for (int e = 0; e < Esz; ++e) alpha_s[e] *= inv;
    }
    __syncthreads();

    for (int hh = tid; hh < Hsz; hh += 256) {
        float acc = 0.f;
        for (int e = 0; e < Esz; ++e) acc += alpha_s[e] * l_s[e * Hsz + hh];
        repr_s[hh] = acc;
    }
    __syncthreads();

    if (tid == 0) {
        float acc = dense_b[0];
        for (int hh = 0; hh < Hsz; ++hh) acc += repr_s[hh] * dense_w[hh];
        out[b] = sigmoidf_(acc);
    }
}

// ---------------------------------------------------------------------------
extern "C" void kernel_launch(void* const* d_in, const int* in_sizes, int n_in,
                              void* d_out, int out_size, void* d_ws, size_t ws_size,
                              hipStream_t stream) {
    const float* essays    = (const float*)d_in[0];
    const float* conv_k    = (const float*)d_in[1];
    const float* conv_b    = (const float*)d_in[2];
    const float* att1_mat  = (const float*)d_in[3];
    const float* att1_bias = (const float*)d_in[4];
    const float* att1_vec  = (const float*)d_in[5];
    const float* lstm_W    = (const float*)d_in[6];
    const float* lstm_b    = (const float*)d_in[7];
    const float* att2_mat  = (const float*)d_in[8];
    const float* att2_bias = (const float*)d_in[9];
    const float* att2_vec  = (const float*)d_in[10];
    const float* dense_w   = (const float*)d_in[11];
    const float* dense_b   = (const float*)d_in[12];

    float* out = (float*)d_out;
    float* sent = (float*)d_ws;                    // [B,E,F]
    float* lstm = sent + (size_t)Bsz * Esz * Fsz;  // [B,E,H]

    conv_att1_kernel<<<Bsz * Esz, 256, 0, stream>>>(
        essays, conv_k, conv_b, att1_mat, att1_bias, att1_vec, sent);
    lstm_kernel<<<Bsz, 512, 0, stream>>>(sent, lstm_W, lstm_b, lstm);
    att2_kernel<<<Bsz, 256, 0, stream>>>(
        lstm, att2_mat, att2_bias, att2_vec, dense_w, dense_b, out);
}

// Round 2
// 558.240 us; speedup vs baseline: 8.7475x; 8.7475x over previous
//
#include <hip/hip_runtime.h>
#include <hip/hip_bf16.h>
#include <stdint.h>

// Problem constants
#define Bsz 32
#define Esz 64
#define Ssz 50
#define Dsz 300
#define Fsz 100
#define Hsz 100
#define WWIN 5

// Conv-as-GEMM geometry (per (b,e) block)
#define PX   328          // Xp row pitch in bf16 elems (rows 16B-aligned)
#define PC   136          // conv_bf row pitch in bf16 elems
#define PS   113          // scores row pitch in fp32 elems
#define KT_CONV 50        // K' = 5 windows * 320 = 1600 -> 50 k-tiles of 32
#define NTILES  7         // N = 112 (100 padded)
#define MTILES  4         // M = 64  (50 padded)

typedef __attribute__((ext_vector_type(8))) short bf16x8;
typedef __attribute__((ext_vector_type(4))) float f32x4;

__device__ __forceinline__ float sigmoidf_(float x) { return 1.0f / (1.0f + expf(-x)); }

__device__ __forceinline__ unsigned short f2bf(float x) {
    union { float f; uint32_t u; } v; v.f = x;
    uint32_t r = v.u + 0x7fffu + ((v.u >> 16) & 1u);   // RNE
    return (unsigned short)(r >> 16);
}
__device__ __forceinline__ float bf2f(unsigned short b) {
    union { uint32_t u; float f; } v; v.u = ((uint32_t)b) << 16;
    return v.f;
}

// ---------------------------------------------------------------------------
// Prep kernel: build bf16 MFMA B-operands + transposed LSTM weights.
//  BtgC: [50][112][32] bf16   conv_k padded (d->320 per window, f->112)
//  BtgA: [4][112][32]  bf16   att1_mat padded (k->128, g->112)
//  Wt:   [400][200]    fp32   lstm_W transposed
// ---------------------------------------------------------------------------
#define N_BTGC (KT_CONV * 112 * 32)   // 179200
#define N_BTGA (4 * 112 * 32)         // 14336
#define N_WT   (400 * 200)            // 80000

__global__ __launch_bounds__(256) void prep_kernel(
    const float* __restrict__ conv_k, const float* __restrict__ att1_mat,
    const float* __restrict__ lstm_W,
    unsigned short* __restrict__ BtgC, unsigned short* __restrict__ BtgA,
    float* __restrict__ Wt)
{
    const int total = N_BTGC + N_BTGA + N_WT;
    for (int i = blockIdx.x * 256 + threadIdx.x; i < total; i += gridDim.x * 256) {
        if (i < N_BTGC) {
            const int kt = i / (112 * 32);
            const int r  = i % (112 * 32);
            const int n  = r / 32;
            const int kk = r % 32;
            const int w  = kt / 10;
            const int d  = (kt % 10) * 32 + kk;
            float val = (d < Dsz && n < Fsz) ? conv_k[((size_t)w * Dsz + d) * Fsz + n] : 0.f;
            BtgC[i] = f2bf(val);
        } else if (i < N_BTGC + N_BTGA) {
            const int j  = i - N_BTGC;
            const int kt = j / (112 * 32);
            const int r  = j % (112 * 32);
            const int n  = r / 32;
            const int kk = r % 32;
            const int k  = kt * 32 + kk;
            float val = (k < Fsz && n < Fsz) ? att1_mat[(size_t)k * Fsz + n] : 0.f;
            BtgA[j] = f2bf(val);
        } else {
            const int j = i - N_BTGC - N_BTGA;
            const int g = j / 200;
            const int k = j % 200;
            Wt[j] = lstm_W[(size_t)k * 400 + g];
        }
    }
}

// ---------------------------------------------------------------------------
// Kernel 1 v2: per-(b,e) conv via bf16 MFMA + att1 pooling -> sent[b,e,F]
// grid = B*E blocks, 256 threads (4 waves). Waves split N-tiles.
// ---------------------------------------------------------------------------
__global__ __launch_bounds__(256) void conv_att1_kernel(
    const float* __restrict__ essays,       // [B,E,S,D]
    const unsigned short* __restrict__ BtgC,// [50][112][32] bf16
    const unsigned short* __restrict__ BtgA,// [4][112][32] bf16
    const float* __restrict__ conv_b,       // [F]
    const float* __restrict__ att1_bias,    // [F]
    const float* __restrict__ att1_vec,     // [F]
    float* __restrict__ sent)               // [B,E,F]
{
    __shared__ __align__(16) unsigned short Xp_u[54 * PX];   // 35424 B (scores overlay)
    __shared__ __align__(16) unsigned short convbf[64 * PC]; // 17408 B
    __shared__ float u_s[64];
    __shared__ float alpha_s[64];

    const int be  = blockIdx.x;
    const int tid = threadIdx.x;
    const int lane = tid & 63;
    const int wid  = tid >> 6;           // 0..3
    const int ln   = lane & 15;
    const int qd   = lane >> 4;          // 0..3
    const float* in_g = essays + (size_t)be * (Ssz * Dsz);

    // ---- stage Xp (bf16, zero-padded rows -2,-1,50,51 and cols 300..327) ----
    for (int idx = tid; idx < 54 * PX; idx += 256) {
        const int r  = idx / PX;
        const int cc = idx % PX;
        const int s  = r - 2;
        float val = (s >= 0 && s < Ssz && cc < Dsz) ? in_g[s * Dsz + cc] : 0.f;
        Xp_u[idx] = f2bf(val);
    }
    // zero conv_bf K-padding cols 112..135 (rows all)
    for (int idx = tid; idx < 64 * 24; idx += 256) {
        const int r = idx / 24, cc = 112 + idx % 24;
        convbf[r * PC + cc] = 0;
    }
    __syncthreads();

    // ---- conv MFMA: M=64, N=112, K'=1600. wave wid owns nt0=wid, nt1=wid+4 ----
    const int nt0 = wid;
    const int nt1 = wid + 4;
    const bool has1 = (nt1 < NTILES);

    f32x4 acc[MTILES][2];
#pragma unroll
    for (int mt = 0; mt < MTILES; ++mt) { acc[mt][0] = (f32x4)0.f; acc[mt][1] = (f32x4)0.f; }

    for (int w = 0; w < WWIN; ++w) {
#pragma unroll
        for (int t = 0; t < 10; ++t) {
            const int kt = w * 10 + t;
            const int d0 = t * 32;
            bf16x8 afrag[MTILES];
#pragma unroll
            for (int mt = 0; mt < MTILES; ++mt) {
                const int m = mt * 16 + ln;
                const int rowx = (m < Ssz ? m : Ssz - 1) + w;   // clamp pad rows
                afrag[mt] = *reinterpret_cast<const bf16x8*>(&Xp_u[rowx * PX + d0 + 8 * qd]);
            }
            const bf16x8 b0 = *reinterpret_cast<const bf16x8*>(
                BtgC + ((size_t)kt * 112 + nt0 * 16 + ln) * 32 + 8 * qd);
            bf16x8 b1 = (bf16x8)0;
            if (has1)
                b1 = *reinterpret_cast<const bf16x8*>(
                    BtgC + ((size_t)kt * 112 + nt1 * 16 + ln) * 32 + 8 * qd);
#pragma unroll
            for (int mt = 0; mt < MTILES; ++mt) {
                acc[mt][0] = __builtin_amdgcn_mfma_f32_16x16x32_bf16(afrag[mt], b0, acc[mt][0], 0, 0, 0);
                if (has1)
                    acc[mt][1] = __builtin_amdgcn_mfma_f32_16x16x32_bf16(afrag[mt], b1, acc[mt][1], 0, 0, 0);
            }
        }
    }
    __syncthreads();   // Xp no longer needed after all waves pass

    // ---- epilogue: bias + relu -> conv_bf (bf16) ----
#pragma unroll
    for (int nl = 0; nl < 2; ++nl) {
        const int nt = (nl == 0) ? nt0 : nt1;
        if (nl == 1 && !has1) break;
        const int n_g = nt * 16 + ln;
        const float bias = (n_g < Fsz) ? conv_b[n_g] : 0.f;
#pragma unroll
        for (int mt = 0; mt < MTILES; ++mt) {
#pragma unroll
            for (int j = 0; j < 4; ++j) {
                const int m_row = mt * 16 + qd * 4 + j;
                const float v = fmaxf(acc[mt][nl][j] + bias, 0.f);
                convbf[m_row * PC + n_g] = f2bf(v);
            }
        }
    }
    __syncthreads();

    // ---- att1 scores MFMA: S = tanh(conv * att1_mat + bias) * vec ----
    float* S = reinterpret_cast<float*>(Xp_u);   // overlay: 64*113*4 = 28928 B
    f32x4 acc2[MTILES][2];
#pragma unroll
    for (int mt = 0; mt < MTILES; ++mt) { acc2[mt][0] = (f32x4)0.f; acc2[mt][1] = (f32x4)0.f; }

#pragma unroll
    for (int kt = 0; kt < 4; ++kt) {
        bf16x8 afrag[MTILES];
#pragma unroll
        for (int mt = 0; mt < MTILES; ++mt) {
            afrag[mt] = *reinterpret_cast<const bf16x8*>(
                &convbf[(mt * 16 + ln) * PC + kt * 32 + 8 * qd]);
        }
        const bf16x8 b0 = *reinterpret_cast<const bf16x8*>(
            BtgA + ((size_t)kt * 112 + nt0 * 16 + ln) * 32 + 8 * qd);
        bf16x8 b1 = (bf16x8)0;
        if (has1)
            b1 = *reinterpret_cast<const bf16x8*>(
                BtgA + ((size_t)kt * 112 + nt1 * 16 + ln) * 32 + 8 * qd);
#pragma unroll
        for (int mt = 0; mt < MTILES; ++mt) {
            acc2[mt][0] = __builtin_amdgcn_mfma_f32_16x16x32_bf16(afrag[mt], b0, acc2[mt][0], 0, 0, 0);
            if (has1)
                acc2[mt][1] = __builtin_amdgcn_mfma_f32_16x16x32_bf16(afrag[mt], b1, acc2[mt][1], 0, 0, 0);
        }
    }

    // scores epilogue -> S (fp32, only g<100 used later)
#pragma unroll
    for (int nl = 0; nl < 2; ++nl) {
        const int nt = (nl == 0) ? nt0 : nt1;
        if (nl == 1 && !has1) break;
        const int n_g = nt * 16 + ln;
        if (n_g < Fsz) {
            const float b1v = att1_bias[n_g];
            const float vv  = att1_vec[n_g];
#pragma unroll
            for (int mt = 0; mt < MTILES; ++mt) {
#pragma unroll
                for (int j = 0; j < 4; ++j) {
                    const int m_row = mt * 16 + qd * 4 + j;
                    S[m_row * PS + n_g] = tanhf(acc2[mt][nl][j] + b1v) * vv;
                }
            }
        }
    }
    __syncthreads();

    // ---- u[s] = row-sum of S over g<100 ----
    if (tid < Ssz) {
        float a = 0.f;
        const float* sp = S + tid * PS;
        for (int g = 0; g < Fsz; ++g) a += sp[g];
        u_s[tid] = a;
    }
    __syncthreads();

    // ---- softmax over s (first wave) ----
    if (tid < 64) {
        const float uv = (tid < Ssz) ? u_s[tid] : -1e30f;
        float m = uv;
#pragma unroll
        for (int off = 32; off > 0; off >>= 1) m = fmaxf(m, __shfl_xor(m, off));
        float e = (tid < Ssz) ? expf(uv - m) : 0.f;
        float sum = e;
#pragma unroll
        for (int off = 32; off > 0; off >>= 1) sum += __shfl_xor(sum, off);
        alpha_s[tid] = e / sum;
    }
    __syncthreads();

    // ---- sent[f] = sum_s alpha[s]*conv[s][f] ----
    if (tid < Fsz) {
        float a = 0.f;
        for (int s = 0; s < Ssz; ++s) a += alpha_s[s] * bf2f(convbf[s * PC + tid]);
        sent[(size_t)be * Fsz + tid] = a;
    }
}

// ---------------------------------------------------------------------------
// Kernel 2 v2: LSTM, transposed weights Wt[400][200], float4 row reads.
// grid = B blocks, 512 threads (400 active for gates)
// ---------------------------------------------------------------------------
__global__ __launch_bounds__(512) void lstm_kernel(
    const float* __restrict__ sent,   // [B,E,F]
    const float* __restrict__ Wt,     // [400][200]
    const float* __restrict__ lstm_b, // [4H]
    float* __restrict__ lstm_out)     // [B,E,H]
{
    __shared__ __align__(16) float x_s[Fsz];
    __shared__ __align__(16) float h_s[Hsz];
    __shared__ float z_s[4 * Hsz];

    const int b = blockIdx.x;
    const int tid = threadIdx.x;
    float c = 0.f;
    if (tid < Hsz) h_s[tid] = 0.f;
    const float bias = (tid < 400) ? lstm_b[tid] : 0.f;
    const float4* Wrow = reinterpret_cast<const float4*>(Wt + (size_t)(tid < 400 ? tid : 0) * 200);
    __syncthreads();

    for (int t = 0; t < Esz; ++t) {
        if (tid < Fsz) x_s[tid] = sent[((size_t)b * Esz + t) * Fsz + tid];
        __syncthreads();

        if (tid < 400) {
            const float4* x4 = reinterpret_cast<const float4*>(x_s);
            const float4* h4 = reinterpret_cast<const float4*>(h_s);
            float s0 = bias, s1 = 0.f, s2 = 0.f, s3 = 0.f;
#pragma unroll 5
            for (int k4 = 0; k4 < 25; ++k4) {
                const float4 w = Wrow[k4];
                const float4 xv = x4[k4];
                s0 += w.x * xv.x; s1 += w.y * xv.y; s2 += w.z * xv.z; s3 += w.w * xv.w;
            }
#pragma unroll 5
            for (int k4 = 0; k4 < 25; ++k4) {
                const float4 w = Wrow[25 + k4];
                const float4 hv = h4[k4];
                s0 += w.x * hv.x; s1 += w.y * hv.y; s2 += w.z * hv.z; s3 += w.w * hv.w;
            }
            z_s[tid] = (s0 + s1) + (s2 + s3);
        }
        __syncthreads();

        if (tid < Hsz) {
            const float zi = z_s[tid];
            const float zj = z_s[tid + Hsz];
            const float zf = z_s[tid + 2 * Hsz];
            const float zo = z_s[tid + 3 * Hsz];
            c = c * sigmoidf_(zf + 1.0f) + sigmoidf_(zi) * tanhf(zj);
            const float h = sigmoidf_(zo) * tanhf(c);
            h_s[tid] = h;
            lstm_out[((size_t)b * Esz + t) * Hsz + tid] = h;
        }
        __syncthreads();
    }
}

// ---------------------------------------------------------------------------
// Kernel 3: attention pooling over sentences + dense + sigmoid -> out[B]
// ---------------------------------------------------------------------------
__global__ __launch_bounds__(256) void att2_kernel(
    const float* __restrict__ lstm,      // [B,E,H]
    const float* __restrict__ att2_mat,  // [H,H]
    const float* __restrict__ att2_bias, // [H]
    const float* __restrict__ att2_vec,  // [H]
    const float* __restrict__ dense_w,   // [H]
    const float* __restrict__ dense_b,   // [1]
    float* __restrict__ out)             // [B]
{
    __shared__ float l_s[Esz * Hsz];
    __shared__ float w2_s[Esz * Hsz];
    __shared__ float u2_s[Esz];
    __shared__ float alpha_s[Esz];
    __shared__ float repr_s[Hsz];

    const int b = blockIdx.x;
    const int tid = threadIdx.x;

    for (int i = tid; i < Esz * Hsz; i += 256) l_s[i] = lstm[(size_t)b * Esz * Hsz + i];
    __syncthreads();

    for (int idx = tid; idx < Esz * Hsz; idx += 256) {
        const int e = idx / Hsz;
        const int g = idx % Hsz;
        const float* lp = l_s + e * Hsz;
        float a0 = 0.f, a1 = 0.f, a2 = 0.f, a3 = 0.f;
        for (int h4 = 0; h4 < Hsz; h4 += 4) {
            a0 += lp[h4 + 0] * att2_mat[(h4 + 0) * Hsz + g];
            a1 += lp[h4 + 1] * att2_mat[(h4 + 1) * Hsz + g];
            a2 += lp[h4 + 2] * att2_mat[(h4 + 2) * Hsz + g];
            a3 += lp[h4 + 3] * att2_mat[(h4 + 3) * Hsz + g];
        }
        const float t = tanhf(att2_bias[g] + ((a0 + a1) + (a2 + a3)));
        w2_s[idx] = t * att2_vec[g];
    }
    __syncthreads();

    for (int e = tid; e < Esz; e += 256) {
        float acc = 0.f;
        const float* wp = w2_s + e * Hsz;
        for (int g = 0; g < Hsz; ++g) acc += wp[g];
        u2_s[e] = acc;
    }
    __syncthreads();

    if (tid < 64) {
        const float uv = u2_s[tid];
        float m = uv;
#pragma unroll
        for (int off = 32; off > 0; off >>= 1) m = fmaxf(m, __shfl_xor(m, off));
        float e = expf(uv - m);
        float sum = e;
#pragma unroll
        for (int off = 32; off > 0; off >>= 1) sum += __shfl_xor(sum, off);
        alpha_s[tid] = e / sum;
    }
    __syncthreads();

    for (int hh = tid; hh < Hsz; hh += 256) {
        float acc = 0.f;
        for (int e = 0; e < Esz; ++e) acc += alpha_s[e] * l_s[e * Hsz + hh];
        repr_s[hh] = acc;
    }
    __syncthreads();

    if (tid == 0) {
        float acc = dense_b[0];
        for (int hh = 0; hh < Hsz; ++hh) acc += repr_s[hh] * dense_w[hh];
        out[b] = sigmoidf_(acc);
    }
}

// ---------------------------------------------------------------------------
extern "C" void kernel_launch(void* const* d_in, const int* in_sizes, int n_in,
                              void* d_out, int out_size, void* d_ws, size_t ws_size,
                              hipStream_t stream) {
    const float* essays    = (const float*)d_in[0];
    const float* conv_k    = (const float*)d_in[1];
    const float* conv_b    = (const float*)d_in[2];
    const float* att1_mat  = (const float*)d_in[3];
    const float* att1_bias = (const float*)d_in[4];
    const float* att1_vec  = (const float*)d_in[5];
    const float* lstm_W    = (const float*)d_in[6];
    const float* lstm_b    = (const float*)d_in[7];
    const float* att2_mat  = (const float*)d_in[8];
    const float* att2_bias = (const float*)d_in[9];
    const float* att2_vec  = (const float*)d_in[10];
    const float* dense_w   = (const float*)d_in[11];
    const float* dense_b   = (const float*)d_in[12];

    float* out = (float*)d_out;

    // workspace layout (256B aligned chunks)
    char* ws = (char*)d_ws;
    float* sent = (float*)ws;                                   // 819200 B
    float* lstm = (float*)(ws + 819200);                        // 819200 B
    unsigned short* BtgC = (unsigned short*)(ws + 1638400);     // 358400 B
    unsigned short* BtgA = (unsigned short*)(ws + 1996800);     // 28672 B
    float* Wt = (float*)(ws + 2025472);                         // 320000 B

    prep_kernel<<<512, 256, 0, stream>>>(conv_k, att1_mat, lstm_W, BtgC, BtgA, Wt);
    conv_att1_kernel<<<Bsz * Esz, 256, 0, stream>>>(
        essays, BtgC, BtgA, conv_b, att1_bias, att1_vec, sent);
    lstm_kernel<<<Bsz, 512, 0, stream>>>(sent, Wt, lstm_b, lstm);
    att2_kernel<<<Bsz, 256, 0, stream>>>(
        lstm, att2_mat, att2_bias, att2_vec, dense_w, dense_b, out);
}

// Round 3
// 300.453 us; speedup vs baseline: 16.2528x; 1.8580x over previous
//
#include <hip/hip_runtime.h>
#include <hip/hip_bf16.h>
#include <stdint.h>

// Problem constants
#define Bsz 32
#define Esz 64
#define Ssz 50
#define Dsz 300
#define Fsz 100
#define Hsz 100
#define WWIN 5

// Conv-as-GEMM geometry (per (b,e) block)
#define PX   328          // Xp row pitch in bf16 elems
#define PC   136          // conv_bf row pitch in bf16 elems
#define PS   113          // scores row pitch in fp32 elems
#define KT_CONV 50        // K' = 5 windows * 320 = 1600 -> 50 k-tiles of 32
#define NTILES  7         // N = 112 (100 padded)
#define MTILES  4         // M = 64  (50 padded)

typedef __attribute__((ext_vector_type(8))) short bf16x8;
typedef __attribute__((ext_vector_type(4))) float f32x4;

__device__ __forceinline__ float sigmoidf_(float x) { return 1.0f / (1.0f + expf(-x)); }

__device__ __forceinline__ unsigned short f2bf(float x) {
    union { float f; uint32_t u; } v; v.f = x;
    uint32_t r = v.u + 0x7fffu + ((v.u >> 16) & 1u);   // RNE
    return (unsigned short)(r >> 16);
}
__device__ __forceinline__ float bf2f(unsigned short b) {
    union { uint32_t u; float f; } v; v.u = ((uint32_t)b) << 16;
    return v.f;
}

// ---------------------------------------------------------------------------
// Prep kernel: bf16 MFMA B-operands.
//  BtgC: [50][112][32] bf16   conv_k padded (d->320 per window, f->112)
//  BtgA: [4][112][32]  bf16   att1_mat padded (k->128, g->112)
//  BtgW: [4][400][32]  bf16   lstm_W x-part rows 0..99 padded (k->128), n=400
// ---------------------------------------------------------------------------
#define N_BTGC (KT_CONV * 112 * 32)   // 179200
#define N_BTGA (4 * 112 * 32)         // 14336
#define N_BTGW (4 * 400 * 32)         // 51200

__global__ __launch_bounds__(256) void prep_kernel(
    const float* __restrict__ conv_k, const float* __restrict__ att1_mat,
    const float* __restrict__ lstm_W,
    unsigned short* __restrict__ BtgC, unsigned short* __restrict__ BtgA,
    unsigned short* __restrict__ BtgW)
{
    const int total = N_BTGC + N_BTGA + N_BTGW;
    for (int i = blockIdx.x * 256 + threadIdx.x; i < total; i += gridDim.x * 256) {
        if (i < N_BTGC) {
            const int kt = i / (112 * 32);
            const int r  = i % (112 * 32);
            const int n  = r / 32;
            const int kk = r % 32;
            const int w  = kt / 10;
            const int d  = (kt % 10) * 32 + kk;
            float val = (d < Dsz && n < Fsz) ? conv_k[((size_t)w * Dsz + d) * Fsz + n] : 0.f;
            BtgC[i] = f2bf(val);
        } else if (i < N_BTGC + N_BTGA) {
            const int j  = i - N_BTGC;
            const int kt = j / (112 * 32);
            const int r  = j % (112 * 32);
            const int n  = r / 32;
            const int kk = r % 32;
            const int k  = kt * 32 + kk;
            float val = (k < Fsz && n < Fsz) ? att1_mat[(size_t)k * Fsz + n] : 0.f;
            BtgA[j] = f2bf(val);
        } else {
            const int j  = i - N_BTGC - N_BTGA;
            const int kt = j / (400 * 32);
            const int r  = j % (400 * 32);
            const int n  = r / 32;
            const int kk = r % 32;
            const int k  = kt * 32 + kk;
            float val = (k < Fsz) ? lstm_W[(size_t)k * 400 + n] : 0.f;
            BtgW[j] = f2bf(val);
        }
    }
}

// ---------------------------------------------------------------------------
// Kernel 1: per-(b,e) conv via bf16 MFMA + att1 pooling -> sent_bf[be][128]
// grid = B*E blocks, 256 threads (4 waves). Waves split N-tiles.
// ---------------------------------------------------------------------------
__global__ __launch_bounds__(256) void conv_att1_kernel(
    const float* __restrict__ essays,       // [B,E,S,D]
    const unsigned short* __restrict__ BtgC,// [50][112][32] bf16
    const unsigned short* __restrict__ BtgA,// [4][112][32] bf16
    const float* __restrict__ conv_b,       // [F]
    const float* __restrict__ att1_bias,    // [F]
    const float* __restrict__ att1_vec,     // [F]
    unsigned short* __restrict__ sent_bf)   // [2048][128] bf16 (cols 100..127 = 0)
{
    __shared__ __align__(16) unsigned short Xp_u[54 * PX];   // 35424 B (scores overlay)
    __shared__ __align__(16) unsigned short convbf[64 * PC]; // 17408 B
    __shared__ float u_s[64];
    __shared__ float alpha_s[64];

    const int be  = blockIdx.x;
    const int tid = threadIdx.x;
    const int lane = tid & 63;
    const int wid  = tid >> 6;           // 0..3
    const int ln   = lane & 15;
    const int qd   = lane >> 4;          // 0..3
    const float* in_g = essays + (size_t)be * (Ssz * Dsz);

    // ---- stage Xp (bf16, zero-padded rows -2,-1,50,51 and cols 300..327) ----
    for (int idx = tid; idx < 54 * PX; idx += 256) {
        const int r  = idx / PX;
        const int cc = idx % PX;
        const int s  = r - 2;
        float val = (s >= 0 && s < Ssz && cc < Dsz) ? in_g[s * Dsz + cc] : 0.f;
        Xp_u[idx] = f2bf(val);
    }
    // zero conv_bf K-padding cols 112..135
    for (int idx = tid; idx < 64 * 24; idx += 256) {
        const int r = idx / 24, cc = 112 + idx % 24;
        convbf[r * PC + cc] = 0;
    }
    __syncthreads();

    // ---- conv MFMA: M=64, N=112, K'=1600. wave wid owns nt0=wid, nt1=wid+4 ----
    const int nt0 = wid;
    const int nt1 = wid + 4;
    const bool has1 = (nt1 < NTILES);

    f32x4 acc[MTILES][2];
#pragma unroll
    for (int mt = 0; mt < MTILES; ++mt) { acc[mt][0] = (f32x4)0.f; acc[mt][1] = (f32x4)0.f; }

    for (int w = 0; w < WWIN; ++w) {
#pragma unroll
        for (int t = 0; t < 10; ++t) {
            const int kt = w * 10 + t;
            const int d0 = t * 32;
            bf16x8 afrag[MTILES];
#pragma unroll
            for (int mt = 0; mt < MTILES; ++mt) {
                const int m = mt * 16 + ln;
                const int rowx = (m < Ssz ? m : Ssz - 1) + w;   // clamp pad rows
                afrag[mt] = *reinterpret_cast<const bf16x8*>(&Xp_u[rowx * PX + d0 + 8 * qd]);
            }
            const bf16x8 b0 = *reinterpret_cast<const bf16x8*>(
                BtgC + ((size_t)kt * 112 + nt0 * 16 + ln) * 32 + 8 * qd);
            bf16x8 b1 = (bf16x8)0;
            if (has1)
                b1 = *reinterpret_cast<const bf16x8*>(
                    BtgC + ((size_t)kt * 112 + nt1 * 16 + ln) * 32 + 8 * qd);
#pragma unroll
            for (int mt = 0; mt < MTILES; ++mt) {
                acc[mt][0] = __builtin_amdgcn_mfma_f32_16x16x32_bf16(afrag[mt], b0, acc[mt][0], 0, 0, 0);
                if (has1)
                    acc[mt][1] = __builtin_amdgcn_mfma_f32_16x16x32_bf16(afrag[mt], b1, acc[mt][1], 0, 0, 0);
            }
        }
    }
    __syncthreads();

    // ---- epilogue: bias + relu -> conv_bf (bf16) ----
#pragma unroll
    for (int nl = 0; nl < 2; ++nl) {
        const int nt = (nl == 0) ? nt0 : nt1;
        if (nl == 1 && !has1) break;
        const int n_g = nt * 16 + ln;
        const float bias = (n_g < Fsz) ? conv_b[n_g] : 0.f;
#pragma unroll
        for (int mt = 0; mt < MTILES; ++mt) {
#pragma unroll
            for (int j = 0; j < 4; ++j) {
                const int m_row = mt * 16 + qd * 4 + j;
                const float v = fmaxf(acc[mt][nl][j] + bias, 0.f);
                convbf[m_row * PC + n_g] = f2bf(v);
            }
        }
    }
    __syncthreads();

    // ---- att1 scores MFMA ----
    float* S = reinterpret_cast<float*>(Xp_u);   // overlay
    f32x4 acc2[MTILES][2];
#pragma unroll
    for (int mt = 0; mt < MTILES; ++mt) { acc2[mt][0] = (f32x4)0.f; acc2[mt][1] = (f32x4)0.f; }

#pragma unroll
    for (int kt = 0; kt < 4; ++kt) {
        bf16x8 afrag[MTILES];
#pragma unroll
        for (int mt = 0; mt < MTILES; ++mt) {
            afrag[mt] = *reinterpret_cast<const bf16x8*>(
                &convbf[(mt * 16 + ln) * PC + kt * 32 + 8 * qd]);
        }
        const bf16x8 b0 = *reinterpret_cast<const bf16x8*>(
            BtgA + ((size_t)kt * 112 + nt0 * 16 + ln) * 32 + 8 * qd);
        bf16x8 b1 = (bf16x8)0;
        if (has1)
            b1 = *reinterpret_cast<const bf16x8*>(
                BtgA + ((size_t)kt * 112 + nt1 * 16 + ln) * 32 + 8 * qd);
#pragma unroll
        for (int mt = 0; mt < MTILES; ++mt) {
            acc2[mt][0] = __builtin_amdgcn_mfma_f32_16x16x32_bf16(afrag[mt], b0, acc2[mt][0], 0, 0, 0);
            if (has1)
                acc2[mt][1] = __builtin_amdgcn_mfma_f32_16x16x32_bf16(afrag[mt], b1, acc2[mt][1], 0, 0, 0);
        }
    }

#pragma unroll
    for (int nl = 0; nl < 2; ++nl) {
        const int nt = (nl == 0) ? nt0 : nt1;
        if (nl == 1 && !has1) break;
        const int n_g = nt * 16 + ln;
        if (n_g < Fsz) {
            const float b1v = att1_bias[n_g];
            const float vv  = att1_vec[n_g];
#pragma unroll
            for (int mt = 0; mt < MTILES; ++mt) {
#pragma unroll
                for (int j = 0; j < 4; ++j) {
                    const int m_row = mt * 16 + qd * 4 + j;
                    S[m_row * PS + n_g] = tanhf(acc2[mt][nl][j] + b1v) * vv;
                }
            }
        }
    }
    __syncthreads();

    // ---- u[s] = row-sum of S over g<100 ----
    if (tid < Ssz) {
        float a = 0.f;
        const float* sp = S + tid * PS;
        for (int g = 0; g < Fsz; ++g) a += sp[g];
        u_s[tid] = a;
    }
    __syncthreads();

    // ---- softmax over s (first wave) ----
    if (tid < 64) {
        const float uv = (tid < Ssz) ? u_s[tid] : -1e30f;
        float m = uv;
#pragma unroll
        for (int off = 32; off > 0; off >>= 1) m = fmaxf(m, __shfl_xor(m, off));
        float e = (tid < Ssz) ? expf(uv - m) : 0.f;
        float sum = e;
#pragma unroll
        for (int off = 32; off > 0; off >>= 1) sum += __shfl_xor(sum, off);
        alpha_s[tid] = e / sum;
    }
    __syncthreads();

    // ---- sent_bf[be][tid] = sum_s alpha[s]*conv[s][tid], bf16, padded to 128 ----
    if (tid < 128) {
        unsigned short v = 0;
        if (tid < Fsz) {
            float a = 0.f;
            for (int s = 0; s < Ssz; ++s) a += alpha_s[s] * bf2f(convbf[s * PC + tid]);
            v = f2bf(a);
        }
        sent_bf[(size_t)be * 128 + tid] = v;
    }
}

// ---------------------------------------------------------------------------
// Kernel 1b: xpart = sent_bf @ Wx + lstm_b  -> [2048][400] fp32
// grid = 128 blocks (one Mtile16 each), 64 threads (1 wave)
// ---------------------------------------------------------------------------
__global__ __launch_bounds__(64) void xpart_kernel(
    const unsigned short* __restrict__ sent_bf, // [2048][128]
    const unsigned short* __restrict__ BtgW,    // [4][400][32]
    const float* __restrict__ lstm_b,           // [400]
    float* __restrict__ xpart)                  // [2048][400]
{
    const int mt   = blockIdx.x;      // 0..127
    const int lane = threadIdx.x;
    const int ln   = lane & 15;
    const int qd   = lane >> 4;
    const int m0   = mt * 16;

    f32x4 acc[25];
#pragma unroll
    for (int nt = 0; nt < 25; ++nt) acc[nt] = (f32x4)0.f;

#pragma unroll
    for (int kt = 0; kt < 4; ++kt) {
        const bf16x8 a = *reinterpret_cast<const bf16x8*>(
            sent_bf + (size_t)(m0 + ln) * 128 + kt * 32 + 8 * qd);
#pragma unroll
        for (int nt = 0; nt < 25; ++nt) {
            const bf16x8 b = *reinterpret_cast<const bf16x8*>(
                BtgW + ((size_t)kt * 400 + nt * 16 + ln) * 32 + 8 * qd);
            acc[nt] = __builtin_amdgcn_mfma_f32_16x16x32_bf16(a, b, acc[nt], 0, 0, 0);
        }
    }

#pragma unroll
    for (int nt = 0; nt < 25; ++nt) {
        const int col = nt * 16 + ln;
        const float bias = lstm_b[col];
#pragma unroll
        for (int j = 0; j < 4; ++j) {
            const int row = m0 + qd * 4 + j;
            xpart[(size_t)row * 400 + col] = acc[nt][j] + bias;
        }
    }
}

// ---------------------------------------------------------------------------
// Kernel 2 v3: LSTM recurrence, Wh columns register-resident.
// grid = B blocks, 448 threads (400 active)
// ---------------------------------------------------------------------------
__global__ __launch_bounds__(448) void lstm_kernel(
    const float* __restrict__ xpart,   // [2048][400] (bias included)
    const float* __restrict__ lstm_W,  // [200][400]
    float* __restrict__ lstm_out)      // [B,E,H]
{
    __shared__ __align__(16) float h_s[Hsz];
    __shared__ float z_s[400];

    const int b = blockIdx.x;
    const int tid = threadIdx.x;
    const bool actv = tid < 400;

    float w[100];
    if (actv) {
#pragma unroll
        for (int k = 0; k < 100; ++k) w[k] = lstm_W[(size_t)(Fsz + k) * 400 + tid];
    }
    float c = 0.f;
    if (tid < Hsz) h_s[tid] = 0.f;
    __syncthreads();

    float xp_cur = actv ? xpart[(size_t)b * Esz * 400 + tid] : 0.f;
    const float4* h4 = reinterpret_cast<const float4*>(h_s);

    for (int t = 0; t < Esz; ++t) {
        const float xp_next = (actv && (t + 1) < Esz)
            ? xpart[((size_t)b * Esz + t + 1) * 400 + tid] : 0.f;
        if (actv) {
            float z0 = xp_cur, z1 = 0.f, z2 = 0.f, z3 = 0.f;
#pragma unroll
            for (int k4 = 0; k4 < 25; ++k4) {
                const float4 hv = h4[k4];
                z0 += hv.x * w[4 * k4 + 0];
                z1 += hv.y * w[4 * k4 + 1];
                z2 += hv.z * w[4 * k4 + 2];
                z3 += hv.w * w[4 * k4 + 3];
            }
            z_s[tid] = (z0 + z1) + (z2 + z3);
        }
        __syncthreads();

        if (tid < Hsz) {
            const float zi = z_s[tid];
            const float zj = z_s[tid + 100];
            const float zf = z_s[tid + 200];
            const float zo = z_s[tid + 300];
            c = c * sigmoidf_(zf + 1.0f) + sigmoidf_(zi) * tanhf(zj);
            const float h = sigmoidf_(zo) * tanhf(c);
            h_s[tid] = h;
            lstm_out[((size_t)b * Esz + t) * Hsz + tid] = h;
        }
        __syncthreads();
        xp_cur = xp_next;
    }
}

// ---------------------------------------------------------------------------
// Kernel 3: attention pooling over sentences + dense + sigmoid -> out[B]
// ---------------------------------------------------------------------------
__global__ __launch_bounds__(256) void att2_kernel(
    const float* __restrict__ lstm,      // [B,E,H]
    const float* __restrict__ att2_mat,  // [H,H]
    const float* __restrict__ att2_bias, // [H]
    const float* __restrict__ att2_vec,  // [H]
    const float* __restrict__ dense_w,   // [H]
    const float* __restrict__ dense_b,   // [1]
    float* __restrict__ out)             // [B]
{
    __shared__ float l_s[Esz * Hsz];
    __shared__ float w2_s[Esz * Hsz];
    __shared__ float u2_s[Esz];
    __shared__ float alpha_s[Esz];
    __shared__ float repr_s[Hsz];

    const int b = blockIdx.x;
    const int tid = threadIdx.x;

    for (int i = tid; i < Esz * Hsz; i += 256) l_s[i] = lstm[(size_t)b * Esz * Hsz + i];
    __syncthreads();

    for (int idx = tid; idx < Esz * Hsz; idx += 256) {
        const int e = idx / Hsz;
        const int g = idx % Hsz;
        const float* lp = l_s + e * Hsz;
        float a0 = 0.f, a1 = 0.f, a2 = 0.f, a3 = 0.f;
        for (int h4 = 0; h4 < Hsz; h4 += 4) {
            a0 += lp[h4 + 0] * att2_mat[(h4 + 0) * Hsz + g];
            a1 += lp[h4 + 1] * att2_mat[(h4 + 1) * Hsz + g];
            a2 += lp[h4 + 2] * att2_mat[(h4 + 2) * Hsz + g];
            a3 += lp[h4 + 3] * att2_mat[(h4 + 3) * Hsz + g];
        }
        const float t = tanhf(att2_bias[g] + ((a0 + a1) + (a2 + a3)));
        w2_s[idx] = t * att2_vec[g];
    }
    __syncthreads();

    for (int e = tid; e < Esz; e += 256) {
        float acc = 0.f;
        const float* wp = w2_s + e * Hsz;
        for (int g = 0; g < Hsz; ++g) acc += wp[g];
        u2_s[e] = acc;
    }
    __syncthreads();

    if (tid < 64) {
        const float uv = u2_s[tid];
        float m = uv;
#pragma unroll
        for (int off = 32; off > 0; off >>= 1) m = fmaxf(m, __shfl_xor(m, off));
        float e = expf(uv - m);
        float sum = e;
#pragma unroll
        for (int off = 32; off > 0; off >>= 1) sum += __shfl_xor(sum, off);
        alpha_s[tid] = e / sum;
    }
    __syncthreads();

    for (int hh = tid; hh < Hsz; hh += 256) {
        float acc = 0.f;
        for (int e = 0; e < Esz; ++e) acc += alpha_s[e] * l_s[e * Hsz + hh];
        repr_s[hh] = acc;
    }
    __syncthreads();

    if (tid == 0) {
        float acc = dense_b[0];
        for (int hh = 0; hh < Hsz; ++hh) acc += repr_s[hh] * dense_w[hh];
        out[b] = sigmoidf_(acc);
    }
}

// ---------------------------------------------------------------------------
extern "C" void kernel_launch(void* const* d_in, const int* in_sizes, int n_in,
                              void* d_out, int out_size, void* d_ws, size_t ws_size,
                              hipStream_t stream) {
    const float* essays    = (const float*)d_in[0];
    const float* conv_k    = (const float*)d_in[1];
    const float* conv_b    = (const float*)d_in[2];
    const float* att1_mat  = (const float*)d_in[3];
    const float* att1_bias = (const float*)d_in[4];
    const float* att1_vec  = (const float*)d_in[5];
    const float* lstm_W    = (const float*)d_in[6];
    const float* lstm_b    = (const float*)d_in[7];
    const float* att2_mat  = (const float*)d_in[8];
    const float* att2_bias = (const float*)d_in[9];
    const float* att2_vec  = (const float*)d_in[10];
    const float* dense_w   = (const float*)d_in[11];
    const float* dense_b   = (const float*)d_in[12];

    float* out = (float*)d_out;

    // workspace layout (256B-aligned chunks)
    char* ws = (char*)d_ws;
    unsigned short* sent_bf = (unsigned short*)ws;              // 524288 B
    float* lstm = (float*)(ws + 524288);                        // 819200 B
    float* xpart = (float*)(ws + 1343488);                      // 3276800 B
    unsigned short* BtgC = (unsigned short*)(ws + 4620288);     // 358400 B
    unsigned short* BtgA = (unsigned short*)(ws + 4978688);     // 28672 B
    unsigned short* BtgW = (unsigned short*)(ws + 5007360);     // 102400 B

    prep_kernel<<<512, 256, 0, stream>>>(conv_k, att1_mat, lstm_W, BtgC, BtgA, BtgW);
    conv_att1_kernel<<<Bsz * Esz, 256, 0, stream>>>(
        essays, BtgC, BtgA, conv_b, att1_bias, att1_vec, sent_bf);
    xpart_kernel<<<128, 64, 0, stream>>>(sent_bf, BtgW, lstm_b, xpart);
    lstm_kernel<<<Bsz, 448, 0, stream>>>(xpart, lstm_W, lstm);
    att2_kernel<<<Bsz, 256, 0, stream>>>(
        lstm, att2_mat, att2_bias, att2_vec, dense_w, dense_b, out);
}

// Round 4
// 243.799 us; speedup vs baseline: 20.0297x; 1.2324x over previous
//
#include <hip/hip_runtime.h>
#include <hip/hip_bf16.h>
#include <stdint.h>

// Problem constants
#define Bsz 32
#define Esz 64
#define Ssz 50
#define Dsz 300
#define Fsz 100
#define Hsz 100
#define WWIN 5

// Conv-as-GEMM geometry (per (b,e) block)
#define PX   328          // Xp row pitch in bf16 elems
#define PC   136          // conv_bf row pitch in bf16 elems
#define KT_CONV 50        // K' = 5 windows * 320 = 1600 -> 50 k-tiles of 32
#define NTILES  7         // N = 112 (100 padded)
#define MTILES  4         // M = 64  (50 padded)
#define NGRP 2214         // 54 rows * 41 groups-of-8

typedef __attribute__((ext_vector_type(8))) short bf16x8;
typedef __attribute__((ext_vector_type(8))) unsigned short u16x8;
typedef __attribute__((ext_vector_type(4))) float f32x4;

__device__ __forceinline__ float sigmoid_fast(float x) {
    return 1.0f / (1.0f + __expf(-x));
}
__device__ __forceinline__ float tanhf_fast(float x) {
    const float ax = fabsf(x);
    const float e = __expf(2.0f * ax);
    const float t = 1.0f - 2.0f / (e + 1.0f);
    return copysignf(t, x);
}

__device__ __forceinline__ unsigned short f2bf(float x) {
    union { float f; uint32_t u; } v; v.f = x;
    uint32_t r = v.u + 0x7fffu + ((v.u >> 16) & 1u);   // RNE
    return (unsigned short)(r >> 16);
}
__device__ __forceinline__ float bf2f(unsigned short b) {
    union { uint32_t u; float f; } v; v.u = ((uint32_t)b) << 16;
    return v.f;
}

// ---------------------------------------------------------------------------
// Prep kernel: bf16 MFMA B-operands.
//  BtgC: [50][112][32] bf16   conv_k padded (d->320 per window, f->112)
//  BtgA: [4][112][32]  bf16   att1_mat padded (k->128, g->112)
//  BtgW: [4][400][32]  bf16   lstm_W x-part rows 0..99 padded (k->128), n=400
// ---------------------------------------------------------------------------
#define N_BTGC (KT_CONV * 112 * 32)   // 179200
#define N_BTGA (4 * 112 * 32)         // 14336
#define N_BTGW (4 * 400 * 32)         // 51200

__global__ __launch_bounds__(256) void prep_kernel(
    const float* __restrict__ conv_k, const float* __restrict__ att1_mat,
    const float* __restrict__ lstm_W,
    unsigned short* __restrict__ BtgC, unsigned short* __restrict__ BtgA,
    unsigned short* __restrict__ BtgW)
{
    const int total = N_BTGC + N_BTGA + N_BTGW;
    for (int i = blockIdx.x * 256 + threadIdx.x; i < total; i += gridDim.x * 256) {
        if (i < N_BTGC) {
            const int kt = i / (112 * 32);
            const int r  = i % (112 * 32);
            const int n  = r / 32;
            const int kk = r % 32;
            const int w  = kt / 10;
            const int d  = (kt % 10) * 32 + kk;
            float val = (d < Dsz && n < Fsz) ? conv_k[((size_t)w * Dsz + d) * Fsz + n] : 0.f;
            BtgC[i] = f2bf(val);
        } else if (i < N_BTGC + N_BTGA) {
            const int j  = i - N_BTGC;
            const int kt = j / (112 * 32);
            const int r  = j % (112 * 32);
            const int n  = r / 32;
            const int kk = r % 32;
            const int k  = kt * 32 + kk;
            float val = (k < Fsz && n < Fsz) ? att1_mat[(size_t)k * Fsz + n] : 0.f;
            BtgA[j] = f2bf(val);
        } else {
            const int j  = i - N_BTGC - N_BTGA;
            const int kt = j / (400 * 32);
            const int r  = j % (400 * 32);
            const int n  = r / 32;
            const int kk = r % 32;
            const int k  = kt * 32 + kk;
            float val = (k < Fsz) ? lstm_W[(size_t)k * 400 + n] : 0.f;
            BtgW[j] = f2bf(val);
        }
    }
}

// ---------------------------------------------------------------------------
// Kernel 1: per-(b,e) conv via bf16 MFMA + att1 pooling -> sent_bf[be][128]
// grid = B*E blocks, 256 threads (4 waves). Waves split N-tiles.
// LDS: single 35.4 KB buffer; Xp lives there during conv, convbf overlays it
// afterwards. Scores are reduced in-register (shfl) + LDS atomics -> no S.
// ---------------------------------------------------------------------------
__global__ __launch_bounds__(256, 4) void conv_att1_kernel(
    const float* __restrict__ essays,       // [B,E,S,D]
    const unsigned short* __restrict__ BtgC,// [50][112][32] bf16
    const unsigned short* __restrict__ BtgA,// [4][112][32] bf16
    const float* __restrict__ conv_b,       // [F]
    const float* __restrict__ att1_bias,    // [F]
    const float* __restrict__ att1_vec,     // [F]
    unsigned short* __restrict__ sent_bf)   // [2048][128] bf16 (cols 100..127 = 0)
{
    __shared__ __align__(16) unsigned short buf[54 * PX];   // 35424 B
    __shared__ float u_s[64];
    __shared__ float alpha_s[64];

    const int be  = blockIdx.x;
    const int tid = threadIdx.x;
    const int lane = tid & 63;
    const int wid  = tid >> 6;           // 0..3
    const int ln   = lane & 15;
    const int qd   = lane >> 4;          // 0..3
    const float* in_g = essays + (size_t)be * (Ssz * Dsz);

    if (tid < 64) u_s[tid] = 0.f;

    // ---- stage Xp (bf16, zero-padded rows -2,-1,50,51 and cols 300..327) ----
    // 2214 groups of 8 elems; 9 per thread; loads batched, then converted.
    {
        float4 va[9], vb[9];
        int rr[9], cc[9];
        bool hv[9], fv[9], gv[9];
#pragma unroll
        for (int it = 0; it < 9; ++it) {
            const int g  = tid + it * 256;
            const int r  = g / 41;
            const int c8 = (g - r * 41) * 8;
            const int s  = r - 2;
            gv[it] = (g < NGRP);
            hv[it] = gv[it] && (s >= 0) && (s < Ssz) && (c8 < Dsz);
            fv[it] = hv[it] && (c8 + 8 <= Dsz);
            const float* base = in_g + (hv[it] ? (s * Dsz + c8) : 0);
            va[it] = *reinterpret_cast<const float4*>(base);
            vb[it] = *reinterpret_cast<const float4*>(fv[it] ? base + 4 : base);
            rr[it] = r; cc[it] = c8;
        }
#pragma unroll
        for (int it = 0; it < 9; ++it) {
            if (!gv[it]) continue;
            u16x8 o;
            o[0] = hv[it] ? f2bf(va[it].x) : (unsigned short)0;
            o[1] = hv[it] ? f2bf(va[it].y) : (unsigned short)0;
            o[2] = hv[it] ? f2bf(va[it].z) : (unsigned short)0;
            o[3] = hv[it] ? f2bf(va[it].w) : (unsigned short)0;
            o[4] = fv[it] ? f2bf(vb[it].x) : (unsigned short)0;
            o[5] = fv[it] ? f2bf(vb[it].y) : (unsigned short)0;
            o[6] = fv[it] ? f2bf(vb[it].z) : (unsigned short)0;
            o[7] = fv[it] ? f2bf(vb[it].w) : (unsigned short)0;
            *reinterpret_cast<u16x8*>(&buf[rr[it] * PX + cc[it]]) = o;
        }
    }
    __syncthreads();

    // ---- conv MFMA: M=64, N=112, K'=1600. wave wid owns nt0=wid, nt1=wid+4 ----
    const int nt0 = wid;
    const int nt1 = wid + 4;
    const bool has1 = (nt1 < NTILES);

    f32x4 acc[MTILES][2];
#pragma unroll
    for (int mt = 0; mt < MTILES; ++mt) { acc[mt][0] = (f32x4)0.f; acc[mt][1] = (f32x4)0.f; }

    for (int w = 0; w < WWIN; ++w) {
#pragma unroll
        for (int t = 0; t < 10; ++t) {
            const int kt = w * 10 + t;
            const int d0 = t * 32;
            bf16x8 afrag[MTILES];
#pragma unroll
            for (int mt = 0; mt < MTILES; ++mt) {
                const int m = mt * 16 + ln;
                const int rowx = (m < Ssz ? m : Ssz - 1) + w;   // clamp pad rows
                afrag[mt] = *reinterpret_cast<const bf16x8*>(&buf[rowx * PX + d0 + 8 * qd]);
            }
            const bf16x8 b0 = *reinterpret_cast<const bf16x8*>(
                BtgC + ((size_t)kt * 112 + nt0 * 16 + ln) * 32 + 8 * qd);
            bf16x8 b1 = (bf16x8)0;
            if (has1)
                b1 = *reinterpret_cast<const bf16x8*>(
                    BtgC + ((size_t)kt * 112 + nt1 * 16 + ln) * 32 + 8 * qd);
#pragma unroll
            for (int mt = 0; mt < MTILES; ++mt) {
                acc[mt][0] = __builtin_amdgcn_mfma_f32_16x16x32_bf16(afrag[mt], b0, acc[mt][0], 0, 0, 0);
                if (has1)
                    acc[mt][1] = __builtin_amdgcn_mfma_f32_16x16x32_bf16(afrag[mt], b1, acc[mt][1], 0, 0, 0);
            }
        }
    }
    __syncthreads();   // Xp dead from here; convbf overlays buf

    // ---- epilogue: bias + relu -> convbf (bf16, overlaid at buf[0]) ----
#pragma unroll
    for (int nl = 0; nl < 2; ++nl) {
        const int nt = (nl == 0) ? nt0 : nt1;
        if (nl == 1 && !has1) break;
        const int n_g = nt * 16 + ln;
        const float bias = (n_g < Fsz) ? conv_b[n_g] : 0.f;
#pragma unroll
        for (int mt = 0; mt < MTILES; ++mt) {
#pragma unroll
            for (int j = 0; j < 4; ++j) {
                const int m_row = mt * 16 + qd * 4 + j;
                const float v = fmaxf(acc[mt][nl][j] + bias, 0.f);
                buf[m_row * PC + n_g] = f2bf(v);
            }
        }
    }
    // zero K-pad cols 112..127 of convbf (att1 MFMA reads K up to 128)
    for (int idx = tid; idx < 64 * 2; idx += 256) {
        const int row = idx >> 1;
        const int c = 112 + (idx & 1) * 8;
        *reinterpret_cast<u16x8*>(&buf[row * PC + c]) = (u16x8)0;
    }
    __syncthreads();

    // ---- att1 scores MFMA + in-register reduction over g ----
    f32x4 acc2[MTILES][2];
#pragma unroll
    for (int mt = 0; mt < MTILES; ++mt) { acc2[mt][0] = (f32x4)0.f; acc2[mt][1] = (f32x4)0.f; }

#pragma unroll
    for (int kt = 0; kt < 4; ++kt) {
        bf16x8 afrag[MTILES];
#pragma unroll
        for (int mt = 0; mt < MTILES; ++mt) {
            afrag[mt] = *reinterpret_cast<const bf16x8*>(
                &buf[(mt * 16 + ln) * PC + kt * 32 + 8 * qd]);
        }
        const bf16x8 b0 = *reinterpret_cast<const bf16x8*>(
            BtgA + ((size_t)kt * 112 + nt0 * 16 + ln) * 32 + 8 * qd);
        bf16x8 b1 = (bf16x8)0;
        if (has1)
            b1 = *reinterpret_cast<const bf16x8*>(
                BtgA + ((size_t)kt * 112 + nt1 * 16 + ln) * 32 + 8 * qd);
#pragma unroll
        for (int mt = 0; mt < MTILES; ++mt) {
            acc2[mt][0] = __builtin_amdgcn_mfma_f32_16x16x32_bf16(afrag[mt], b0, acc2[mt][0], 0, 0, 0);
            if (has1)
                acc2[mt][1] = __builtin_amdgcn_mfma_f32_16x16x32_bf16(afrag[mt], b1, acc2[mt][1], 0, 0, 0);
        }
    }

    // scores: val = tanh(acc2 + bias)*vec; reduce over 16 ln-lanes; atomic into u_s
#pragma unroll
    for (int nl = 0; nl < 2; ++nl) {
        if (nl == 1 && !has1) break;
        const int nt = (nl == 0) ? nt0 : nt1;
        const int n_g = nt * 16 + ln;
        const bool gval = (n_g < Fsz);
        const float b1v = gval ? att1_bias[n_g] : 0.f;
        const float vv  = gval ? att1_vec[n_g]  : 0.f;
#pragma unroll
        for (int mt = 0; mt < MTILES; ++mt) {
#pragma unroll
            for (int j = 0; j < 4; ++j) {
                const int m_row = mt * 16 + qd * 4 + j;
                float val = (gval && m_row < Ssz)
                    ? tanhf_fast(acc2[mt][nl][j] + b1v) * vv : 0.f;
                val += __shfl_xor(val, 1);
                val += __shfl_xor(val, 2);
                val += __shfl_xor(val, 4);
                val += __shfl_xor(val, 8);
                if (ln == 0 && m_row < Ssz) atomicAdd(&u_s[m_row], val);
            }
        }
    }
    __syncthreads();

    // ---- softmax over s (first wave) ----
    if (tid < 64) {
        const float uv = (tid < Ssz) ? u_s[tid] : -1e30f;
        float m = uv;
#pragma unroll
        for (int off = 32; off > 0; off >>= 1) m = fmaxf(m, __shfl_xor(m, off));
        float e = (tid < Ssz) ? __expf(uv - m) : 0.f;
        float sum = e;
#pragma unroll
        for (int off = 32; off > 0; off >>= 1) sum += __shfl_xor(sum, off);
        alpha_s[tid] = e / sum;
    }
    __syncthreads();

    // ---- sent_bf[be][tid] = sum_s alpha[s]*conv[s][tid], bf16, padded to 128 ----
    if (tid < 128) {
        unsigned short v = 0;
        if (tid < Fsz) {
            float a = 0.f;
            for (int s = 0; s < Ssz; ++s) a += alpha_s[s] * bf2f(buf[s * PC + tid]);
            v = f2bf(a);
        }
        sent_bf[(size_t)be * 128 + tid] = v;
    }
}

// ---------------------------------------------------------------------------
// Kernel 1b: xpart = sent_bf @ Wx + lstm_b  -> [2048][400] fp32
// grid = 32 blocks x 256 threads; wave w handles M-tile blockIdx*4+w
// ---------------------------------------------------------------------------
__global__ __launch_bounds__(256) void xpart_kernel(
    const unsigned short* __restrict__ sent_bf, // [2048][128]
    const unsigned short* __restrict__ BtgW,    // [4][400][32]
    const float* __restrict__ lstm_b,           // [400]
    float* __restrict__ xpart)                  // [2048][400]
{
    const int wid  = threadIdx.x >> 6;
    const int mt   = blockIdx.x * 4 + wid;      // 0..127
    const int lane = threadIdx.x & 63;
    const int ln   = lane & 15;
    const int qd   = lane >> 4;
    const int m0   = mt * 16;

    f32x4 acc[25];
#pragma unroll
    for (int nt = 0; nt < 25; ++nt) acc[nt] = (f32x4)0.f;

#pragma unroll
    for (int kt = 0; kt < 4; ++kt) {
        const bf16x8 a = *reinterpret_cast<const bf16x8*>(
            sent_bf + (size_t)(m0 + ln) * 128 + kt * 32 + 8 * qd);
#pragma unroll
        for (int nt = 0; nt < 25; ++nt) {
            const bf16x8 b = *reinterpret_cast<const bf16x8*>(
                BtgW + ((size_t)kt * 400 + nt * 16 + ln) * 32 + 8 * qd);
            acc[nt] = __builtin_amdgcn_mfma_f32_16x16x32_bf16(a, b, acc[nt], 0, 0, 0);
        }
    }

#pragma unroll
    for (int nt = 0; nt < 25; ++nt) {
        const int col = nt * 16 + ln;
        const float bias = lstm_b[col];
#pragma unroll
        for (int j = 0; j < 4; ++j) {
            const int row = m0 + qd * 4 + j;
            xpart[(size_t)row * 400 + col] = acc[nt][j] + bias;
        }
    }
}

// ---------------------------------------------------------------------------
// Kernel 2: LSTM recurrence, Wh columns register-resident.
// grid = B blocks, 448 threads (400 active)
// ---------------------------------------------------------------------------
__global__ __launch_bounds__(448) void lstm_kernel(
    const float* __restrict__ xpart,   // [2048][400] (bias included)
    const float* __restrict__ lstm_W,  // [200][400]
    float* __restrict__ lstm_out)      // [B,E,H]
{
    __shared__ __align__(16) float h_s[Hsz];
    __shared__ float z_s[400];

    const int b = blockIdx.x;
    const int tid = threadIdx.x;
    const bool actv = tid < 400;

    float w[100];
    if (actv) {
#pragma unroll
        for (int k = 0; k < 100; ++k) w[k] = lstm_W[(size_t)(Fsz + k) * 400 + tid];
    }
    float c = 0.f;
    if (tid < Hsz) h_s[tid] = 0.f;
    __syncthreads();

    float xp_cur = actv ? xpart[(size_t)b * Esz * 400 + tid] : 0.f;
    const float4* h4 = reinterpret_cast<const float4*>(h_s);

    for (int t = 0; t < Esz; ++t) {
        const float xp_next = (actv && (t + 1) < Esz)
            ? xpart[((size_t)b * Esz + t + 1) * 400 + tid] : 0.f;
        if (actv) {
            float z0 = xp_cur, z1 = 0.f, z2 = 0.f, z3 = 0.f;
#pragma unroll
            for (int k4 = 0; k4 < 25; ++k4) {
                const float4 hv = h4[k4];
                z0 += hv.x * w[4 * k4 + 0];
                z1 += hv.y * w[4 * k4 + 1];
                z2 += hv.z * w[4 * k4 + 2];
                z3 += hv.w * w[4 * k4 + 3];
            }
            z_s[tid] = (z0 + z1) + (z2 + z3);
        }
        __syncthreads();

        if (tid < Hsz) {
            const float zi = z_s[tid];
            const float zj = z_s[tid + 100];
            const float zf = z_s[tid + 200];
            const float zo = z_s[tid + 300];
            c = c * sigmoid_fast(zf + 1.0f) + sigmoid_fast(zi) * tanhf_fast(zj);
            const float h = sigmoid_fast(zo) * tanhf_fast(c);
            h_s[tid] = h;
            lstm_out[((size_t)b * Esz + t) * Hsz + tid] = h;
        }
        __syncthreads();
        xp_cur = xp_next;
    }
}

// ---------------------------------------------------------------------------
// Kernel 3: attention pooling over sentences + dense + sigmoid -> out[B]
// ---------------------------------------------------------------------------
__global__ __launch_bounds__(256) void att2_kernel(
    const float* __restrict__ lstm,      // [B,E,H]
    const float* __restrict__ att2_mat,  // [H,H]
    const float* __restrict__ att2_bias, // [H]
    const float* __restrict__ att2_vec,  // [H]
    const float* __restrict__ dense_w,   // [H]
    const float* __restrict__ dense_b,   // [1]
    float* __restrict__ out)             // [B]
{
    __shared__ float l_s[Esz * Hsz];
    __shared__ float w2_s[Esz * Hsz];
    __shared__ float u2_s[Esz];
    __shared__ float alpha_s[Esz];
    __shared__ float repr_s[Hsz];

    const int b = blockIdx.x;
    const int tid = threadIdx.x;

    for (int i = tid; i < Esz * Hsz; i += 256) l_s[i] = lstm[(size_t)b * Esz * Hsz + i];
    __syncthreads();

    for (int idx = tid; idx < Esz * Hsz; idx += 256) {
        const int e = idx / Hsz;
        const int g = idx % Hsz;
        const float* lp = l_s + e * Hsz;
        float a0 = 0.f, a1 = 0.f, a2 = 0.f, a3 = 0.f;
        for (int h4 = 0; h4 < Hsz; h4 += 4) {
            a0 += lp[h4 + 0] * att2_mat[(h4 + 0) * Hsz + g];
            a1 += lp[h4 + 1] * att2_mat[(h4 + 1) * Hsz + g];
            a2 += lp[h4 + 2] * att2_mat[(h4 + 2) * Hsz + g];
            a3 += lp[h4 + 3] * att2_mat[(h4 + 3) * Hsz + g];
        }
        const float t = tanhf_fast(att2_bias[g] + ((a0 + a1) + (a2 + a3)));
        w2_s[idx] = t * att2_vec[g];
    }
    __syncthreads();

    for (int e = tid; e < Esz; e += 256) {
        float acc = 0.f;
        const float* wp = w2_s + e * Hsz;
        for (int g = 0; g < Hsz; ++g) acc += wp[g];
        u2_s[e] = acc;
    }
    __syncthreads();

    if (tid < 64) {
        const float uv = u2_s[tid];
        float m = uv;
#pragma unroll
        for (int off = 32; off > 0; off >>= 1) m = fmaxf(m, __shfl_xor(m, off));
        float e = __expf(uv - m);
        float sum = e;
#pragma unroll
        for (int off = 32; off > 0; off >>= 1) sum += __shfl_xor(sum, off);
        alpha_s[tid] = e / sum;
    }
    __syncthreads();

    for (int hh = tid; hh < Hsz; hh += 256) {
        float acc = 0.f;
        for (int e = 0; e < Esz; ++e) acc += alpha_s[e] * l_s[e * Hsz + hh];
        repr_s[hh] = acc;
    }
    __syncthreads();

    if (tid == 0) {
        float acc = dense_b[0];
        for (int hh = 0; hh < Hsz; ++hh) acc += repr_s[hh] * dense_w[hh];
        out[b] = sigmoid_fast(acc);
    }
}

// ---------------------------------------------------------------------------
extern "C" void kernel_launch(void* const* d_in, const int* in_sizes, int n_in,
                              void* d_out, int out_size, void* d_ws, size_t ws_size,
                              hipStream_t stream) {
    const float* essays    = (const float*)d_in[0];
    const float* conv_k    = (const float*)d_in[1];
    const float* conv_b    = (const float*)d_in[2];
    const float* att1_mat  = (const float*)d_in[3];
    const float* att1_bias = (const float*)d_in[4];
    const float* att1_vec  = (const float*)d_in[5];
    const float* lstm_W    = (const float*)d_in[6];
    const float* lstm_b    = (const float*)d_in[7];
    const float* att2_mat  = (const float*)d_in[8];
    const float* att2_bias = (const float*)d_in[9];
    const float* att2_vec  = (const float*)d_in[10];
    const float* dense_w   = (const float*)d_in[11];
    const float* dense_b   = (const float*)d_in[12];

    float* out = (float*)d_out;

    // workspace layout (256B-aligned chunks)
    char* ws = (char*)d_ws;
    unsigned short* sent_bf = (unsigned short*)ws;              // 524288 B
    float* lstm = (float*)(ws + 524288);                        // 819200 B
    float* xpart = (float*)(ws + 1343488);                      // 3276800 B
    unsigned short* BtgC = (unsigned short*)(ws + 4620288);     // 358400 B
    unsigned short* BtgA = (unsigned short*)(ws + 4978688);     // 28672 B
    unsigned short* BtgW = (unsigned short*)(ws + 5007360);     // 102400 B

    prep_kernel<<<512, 256, 0, stream>>>(conv_k, att1_mat, lstm_W, BtgC, BtgA, BtgW);
    conv_att1_kernel<<<Bsz * Esz, 256, 0, stream>>>(
        essays, BtgC, BtgA, conv_b, att1_bias, att1_vec, sent_bf);
    xpart_kernel<<<32, 256, 0, stream>>>(sent_bf, BtgW, lstm_b, xpart);
    lstm_kernel<<<Bsz, 448, 0, stream>>>(xpart, lstm_W, lstm);
    att2_kernel<<<Bsz, 256, 0, stream>>>(
        lstm, att2_mat, att2_bias, att2_vec, dense_w, dense_b, out);
}

// Round 5
// 211.630 us; speedup vs baseline: 23.0744x; 1.1520x over previous
//
#include <hip/hip_runtime.h>
#include <hip/hip_bf16.h>
#include <stdint.h>

// Problem constants
#define Bsz 32
#define Esz 64
#define Ssz 50
#define Dsz 300
#define Fsz 100
#define Hsz 100
#define WWIN 5

// Conv-as-GEMM geometry (per (b,e) block)
#define PX   328          // Xp row pitch in bf16 elems
#define PC   136          // conv_bf row pitch in bf16 elems
#define KT_CONV 50        // K' = 5 windows * 320 = 1600 -> 50 k-tiles of 32
#define NTILES  7         // N = 112 (100 padded)
#define MTILES  4         // M = 64  (50 padded)
#define NGRP 2214         // 54 rows * 41 groups-of-8

typedef __attribute__((ext_vector_type(8))) short bf16x8;
typedef __attribute__((ext_vector_type(8))) unsigned short u16x8;
typedef __attribute__((ext_vector_type(4))) float f32x4;

__device__ __forceinline__ float sigmoid_fast(float x) {
    return 1.0f / (1.0f + __expf(-x));
}
__device__ __forceinline__ float tanhf_fast(float x) {
    const float ax = fabsf(x);
    const float e = __expf(2.0f * ax);
    const float t = 1.0f - 2.0f / (e + 1.0f);
    return copysignf(t, x);
}

__device__ __forceinline__ unsigned short f2bf(float x) {
    union { __hip_bfloat16 h; unsigned short u; } cv;
    cv.h = __float2bfloat16(x);
    return cv.u;
}
__device__ __forceinline__ unsigned int f2bf2(float lo, float hi) {
    union { __hip_bfloat162 h2; unsigned int u; } cv;
    cv.h2 = __float22bfloat162_rn(make_float2(lo, hi));
    return cv.u;
}
__device__ __forceinline__ float bf2f(unsigned short b) {
    union { uint32_t u; float f; } v; v.u = ((uint32_t)b) << 16;
    return v.f;
}

// ---------------------------------------------------------------------------
// Prep kernel: bf16 MFMA B-operands.
//  BtgC: [50][112][32] bf16   conv_k padded (d->320 per window, f->112)
//  BtgA: [4][112][32]  bf16   att1_mat padded (k->128, g->112)
//  BtgW: [4][400][32]  bf16   lstm_W x-part rows 0..99 padded (k->128), n=400
// ---------------------------------------------------------------------------
#define N_BTGC (KT_CONV * 112 * 32)   // 179200
#define N_BTGA (4 * 112 * 32)         // 14336
#define N_BTGW (4 * 400 * 32)         // 51200

__global__ __launch_bounds__(256) void prep_kernel(
    const float* __restrict__ conv_k, const float* __restrict__ att1_mat,
    const float* __restrict__ lstm_W,
    unsigned short* __restrict__ BtgC, unsigned short* __restrict__ BtgA,
    unsigned short* __restrict__ BtgW)
{
    const int total = N_BTGC + N_BTGA + N_BTGW;
    for (int i = blockIdx.x * 256 + threadIdx.x; i < total; i += gridDim.x * 256) {
        if (i < N_BTGC) {
            const int kt = i / (112 * 32);
            const int r  = i % (112 * 32);
            const int n  = r / 32;
            const int kk = r % 32;
            const int w  = kt / 10;
            const int d  = (kt % 10) * 32 + kk;
            float val = (d < Dsz && n < Fsz) ? conv_k[((size_t)w * Dsz + d) * Fsz + n] : 0.f;
            BtgC[i] = f2bf(val);
        } else if (i < N_BTGC + N_BTGA) {
            const int j  = i - N_BTGC;
            const int kt = j / (112 * 32);
            const int r  = j % (112 * 32);
            const int n  = r / 32;
            const int kk = r % 32;
            const int k  = kt * 32 + kk;
            float val = (k < Fsz && n < Fsz) ? att1_mat[(size_t)k * Fsz + n] : 0.f;
            BtgA[j] = f2bf(val);
        } else {
            const int j  = i - N_BTGC - N_BTGA;
            const int kt = j / (400 * 32);
            const int r  = j % (400 * 32);
            const int n  = r / 32;
            const int kk = r % 32;
            const int k  = kt * 32 + kk;
            float val = (k < Fsz) ? lstm_W[(size_t)k * 400 + n] : 0.f;
            BtgW[j] = f2bf(val);
        }
    }
}

// ---------------------------------------------------------------------------
// Conv K-loop helpers: compile-time kt group indices, register B pipeline.
// ---------------------------------------------------------------------------
template<int G>
__device__ __forceinline__ void conv_loadB(
    const unsigned short* __restrict__ BtgC, int boff0, int boff1, bool has1,
    bf16x8 (&bR)[5][2])
{
#pragma unroll
    for (int i = 0; i < 5; ++i) {
        const int kt = G * 5 + i;
        bR[i][0] = *reinterpret_cast<const bf16x8*>(BtgC + kt * 3584 + boff0);
        bR[i][1] = has1 ? *reinterpret_cast<const bf16x8*>(BtgC + kt * 3584 + boff1)
                        : (bf16x8)0;
    }
}

template<int G>
__device__ __forceinline__ void conv_compute(
    const unsigned short* buf, const int (&abase)[MTILES], bool has1,
    const bf16x8 (&bR)[5][2], f32x4 (&acc)[MTILES][2])
{
#pragma unroll
    for (int i = 0; i < 5; ++i) {
        const int kt  = G * 5 + i;
        const int w   = kt / 10;
        const int t   = kt % 10;
        const int off = w * PX + t * 32;   // compile-time immediate
#pragma unroll
        for (int mt = 0; mt < MTILES; ++mt) {
            const bf16x8 af = *reinterpret_cast<const bf16x8*>(&buf[abase[mt] + off]);
            acc[mt][0] = __builtin_amdgcn_mfma_f32_16x16x32_bf16(af, bR[i][0], acc[mt][0], 0, 0, 0);
            if (has1)
                acc[mt][1] = __builtin_amdgcn_mfma_f32_16x16x32_bf16(af, bR[i][1], acc[mt][1], 0, 0, 0);
        }
    }
}

// ---------------------------------------------------------------------------
// Kernel 1: per-(b,e) conv via bf16 MFMA + att1 pooling -> sent_bf[be][128]
// grid = B*E blocks, 256 threads (4 waves). Waves split N-tiles.
// ---------------------------------------------------------------------------
__global__ __launch_bounds__(256, 3) void conv_att1_kernel(
    const float* __restrict__ essays,       // [B,E,S,D]
    const unsigned short* __restrict__ BtgC,// [50][112][32] bf16
    const unsigned short* __restrict__ BtgA,// [4][112][32] bf16
    const float* __restrict__ conv_b,       // [F]
    const float* __restrict__ att1_bias,    // [F]
    const float* __restrict__ att1_vec,     // [F]
    unsigned short* __restrict__ sent_bf)   // [2048][128] bf16 (cols 100..127 = 0)
{
    __shared__ __align__(16) unsigned short buf[54 * PX];   // 35424 B
    __shared__ float u_s[64];
    __shared__ float alpha_s[64];

    const int be  = blockIdx.x;
    const int tid = threadIdx.x;
    const int lane = tid & 63;
    const int wid  = tid >> 6;           // 0..3
    const int ln   = lane & 15;
    const int qd   = lane >> 4;          // 0..3
    const float* in_g = essays + (size_t)be * (Ssz * Dsz);

    if (tid < 64) u_s[tid] = 0.f;

    // ---- stage Xp (bf16, zero-padded rows -2,-1,50,51 and cols 300..327) ----
    {
        float4 va[9], vb[9];
        int rr[9], cc[9];
        bool hv[9], fv[9], gv[9];
#pragma unroll
        for (int it = 0; it < 9; ++it) {
            const int g  = tid + it * 256;
            const int r  = g / 41;
            const int c8 = (g - r * 41) * 8;
            const int s  = r - 2;
            gv[it] = (g < NGRP);
            hv[it] = gv[it] && (s >= 0) && (s < Ssz) && (c8 < Dsz);
            fv[it] = hv[it] && (c8 + 8 <= Dsz);
            const float* base = in_g + (hv[it] ? (s * Dsz + c8) : 0);
            va[it] = *reinterpret_cast<const float4*>(base);
            vb[it] = *reinterpret_cast<const float4*>(fv[it] ? base + 4 : base);
            rr[it] = r; cc[it] = c8;
        }
#pragma unroll
        for (int it = 0; it < 9; ++it) {
            if (!gv[it]) continue;
            const float e0 = hv[it] ? va[it].x : 0.f;
            const float e1 = hv[it] ? va[it].y : 0.f;
            const float e2 = hv[it] ? va[it].z : 0.f;
            const float e3 = hv[it] ? va[it].w : 0.f;
            const float e4 = fv[it] ? vb[it].x : 0.f;
            const float e5 = fv[it] ? vb[it].y : 0.f;
            const float e6 = fv[it] ? vb[it].z : 0.f;
            const float e7 = fv[it] ? vb[it].w : 0.f;
            uint4 o;
            o.x = f2bf2(e0, e1);
            o.y = f2bf2(e2, e3);
            o.z = f2bf2(e4, e5);
            o.w = f2bf2(e6, e7);
            *reinterpret_cast<uint4*>(&buf[rr[it] * PX + cc[it]]) = o;
        }
    }
    __syncthreads();

    // ---- conv MFMA: M=64, N=112, K'=1600. wave wid owns nt0=wid, nt1=wid+4 ----
    const int nt0 = wid;
    const int nt1 = wid + 4;
    const bool has1 = (nt1 < NTILES);
    const int boff0 = (nt0 * 16 + ln) * 32 + 8 * qd;
    const int boff1 = (nt1 * 16 + ln) * 32 + 8 * qd;

    int abase[MTILES];
#pragma unroll
    for (int mt = 0; mt < MTILES; ++mt) {
        const int m = mt * 16 + ln;
        abase[mt] = (m < Ssz ? m : Ssz - 1) * PX + 8 * qd;
    }

    f32x4 acc[MTILES][2];
#pragma unroll
    for (int mt = 0; mt < MTILES; ++mt) { acc[mt][0] = (f32x4)0.f; acc[mt][1] = (f32x4)0.f; }

    {
        bf16x8 bX[5][2], bY[5][2];
        conv_loadB<0>(BtgC, boff0, boff1, has1, bX);
        conv_loadB<1>(BtgC, boff0, boff1, has1, bY);
        conv_compute<0>(buf, abase, has1, bX, acc);
        conv_loadB<2>(BtgC, boff0, boff1, has1, bX);
        conv_compute<1>(buf, abase, has1, bY, acc);
        conv_loadB<3>(BtgC, boff0, boff1, has1, bY);
        conv_compute<2>(buf, abase, has1, bX, acc);
        conv_loadB<4>(BtgC, boff0, boff1, has1, bX);
        conv_compute<3>(buf, abase, has1, bY, acc);
        conv_loadB<5>(BtgC, boff0, boff1, has1, bY);
        conv_compute<4>(buf, abase, has1, bX, acc);
        conv_loadB<6>(BtgC, boff0, boff1, has1, bX);
        conv_compute<5>(buf, abase, has1, bY, acc);
        conv_loadB<7>(BtgC, boff0, boff1, has1, bY);
        conv_compute<6>(buf, abase, has1, bX, acc);
        conv_loadB<8>(BtgC, boff0, boff1, has1, bX);
        conv_compute<7>(buf, abase, has1, bY, acc);
        conv_loadB<9>(BtgC, boff0, boff1, has1, bY);
        conv_compute<8>(buf, abase, has1, bX, acc);
        conv_compute<9>(buf, abase, has1, bY, acc);
    }

    // issue att1 B loads early (global, independent of LDS overlay)
    bf16x8 a1b[4][2];
#pragma unroll
    for (int kt = 0; kt < 4; ++kt) {
        a1b[kt][0] = *reinterpret_cast<const bf16x8*>(BtgA + kt * 3584 + boff0);
        a1b[kt][1] = has1 ? *reinterpret_cast<const bf16x8*>(BtgA + kt * 3584 + boff1)
                          : (bf16x8)0;
    }
    __syncthreads();   // Xp dead from here; convbf overlays buf

    // ---- epilogue: bias + relu -> convbf (bf16, overlaid at buf[0]) ----
#pragma unroll
    for (int nl = 0; nl < 2; ++nl) {
        const int nt = (nl == 0) ? nt0 : nt1;
        if (nl == 1 && !has1) break;
        const int n_g = nt * 16 + ln;
        const float bias = (n_g < Fsz) ? conv_b[n_g] : 0.f;
#pragma unroll
        for (int mt = 0; mt < MTILES; ++mt) {
#pragma unroll
            for (int j = 0; j < 4; ++j) {
                const int m_row = mt * 16 + qd * 4 + j;
                const float v = fmaxf(acc[mt][nl][j] + bias, 0.f);
                buf[m_row * PC + n_g] = f2bf(v);
            }
        }
    }
    // zero K-pad cols 112..127 of convbf (att1 MFMA reads K up to 128)
    for (int idx = tid; idx < 64 * 2; idx += 256) {
        const int row = idx >> 1;
        const int c = 112 + (idx & 1) * 8;
        *reinterpret_cast<u16x8*>(&buf[row * PC + c]) = (u16x8)0;
    }
    __syncthreads();

    // ---- att1 scores MFMA + in-register reduction over g ----
    f32x4 acc2[MTILES][2];
#pragma unroll
    for (int mt = 0; mt < MTILES; ++mt) { acc2[mt][0] = (f32x4)0.f; acc2[mt][1] = (f32x4)0.f; }

#pragma unroll
    for (int kt = 0; kt < 4; ++kt) {
        bf16x8 afrag[MTILES];
#pragma unroll
        for (int mt = 0; mt < MTILES; ++mt) {
            afrag[mt] = *reinterpret_cast<const bf16x8*>(
                &buf[(mt * 16 + ln) * PC + kt * 32 + 8 * qd]);
        }
#pragma unroll
        for (int mt = 0; mt < MTILES; ++mt) {
            acc2[mt][0] = __builtin_amdgcn_mfma_f32_16x16x32_bf16(afrag[mt], a1b[kt][0], acc2[mt][0], 0, 0, 0);
            if (has1)
                acc2[mt][1] = __builtin_amdgcn_mfma_f32_16x16x32_bf16(afrag[mt], a1b[kt][1], acc2[mt][1], 0, 0, 0);
        }
    }

    // scores: tanh(acc2+bias)*vec; combine both n-tiles, reduce 16 ln-lanes, atomic
    {
        const int g0 = nt0 * 16 + ln;                 // always < 100
        const float b1v0 = att1_bias[g0];
        const float vv0  = att1_vec[g0];
        const int g1 = nt1 * 16 + ln;
        const bool g1v = has1 && (g1 < Fsz);
        const float b1v1 = g1v ? att1_bias[g1] : 0.f;
        const float vv1  = g1v ? att1_vec[g1]  : 0.f;
#pragma unroll
        for (int mt = 0; mt < MTILES; ++mt) {
#pragma unroll
            for (int j = 0; j < 4; ++j) {
                const int m_row = mt * 16 + qd * 4 + j;
                float val = 0.f;
                if (m_row < Ssz) {
                    val = tanhf_fast(acc2[mt][0][j] + b1v0) * vv0;
                    if (g1v) val += tanhf_fast(acc2[mt][1][j] + b1v1) * vv1;
                }
                val += __shfl_xor(val, 1);
                val += __shfl_xor(val, 2);
                val += __shfl_xor(val, 4);
                val += __shfl_xor(val, 8);
                if (ln == 0 && m_row < Ssz) atomicAdd(&u_s[m_row], val);
            }
        }
    }
    __syncthreads();

    // ---- softmax over s (first wave) ----
    if (tid < 64) {
        const float uv = (tid < Ssz) ? u_s[tid] : -1e30f;
        float m = uv;
#pragma unroll
        for (int off = 32; off > 0; off >>= 1) m = fmaxf(m, __shfl_xor(m, off));
        float e = (tid < Ssz) ? __expf(uv - m) : 0.f;
        float sum = e;
#pragma unroll
        for (int off = 32; off > 0; off >>= 1) sum += __shfl_xor(sum, off);
        alpha_s[tid] = e / sum;
    }
    __syncthreads();

    // ---- sent_bf[be][tid] = sum_s alpha[s]*conv[s][tid], bf16, padded to 128 ----
    if (tid < 128) {
        unsigned short v = 0;
        if (tid < Fsz) {
            float a = 0.f;
            for (int s = 0; s < Ssz; ++s) a += alpha_s[s] * bf2f(buf[s * PC + tid]);
            v = f2bf(a);
        }
        sent_bf[(size_t)be * 128 + tid] = v;
    }
}

// ---------------------------------------------------------------------------
// Kernel 1b: xpart = sent_bf @ Wx + lstm_b  -> [2048][400] fp32
// grid = 32 blocks x 256 threads; wave w handles M-tile blockIdx*4+w
// ---------------------------------------------------------------------------
__global__ __launch_bounds__(256) void xpart_kernel(
    const unsigned short* __restrict__ sent_bf, // [2048][128]
    const unsigned short* __restrict__ BtgW,    // [4][400][32]
    const float* __restrict__ lstm_b,           // [400]
    float* __restrict__ xpart)                  // [2048][400]
{
    const int wid  = threadIdx.x >> 6;
    const int mt   = blockIdx.x * 4 + wid;      // 0..127
    const int lane = threadIdx.x & 63;
    const int ln   = lane & 15;
    const int qd   = lane >> 4;
    const int m0   = mt * 16;

    f32x4 acc[25];
#pragma unroll
    for (int nt = 0; nt < 25; ++nt) acc[nt] = (f32x4)0.f;

#pragma unroll
    for (int kt = 0; kt < 4; ++kt) {
        const bf16x8 a = *reinterpret_cast<const bf16x8*>(
            sent_bf + (size_t)(m0 + ln) * 128 + kt * 32 + 8 * qd);
#pragma unroll
        for (int nt = 0; nt < 25; ++nt) {
            const bf16x8 b = *reinterpret_cast<const bf16x8*>(
                BtgW + ((size_t)kt * 400 + nt * 16 + ln) * 32 + 8 * qd);
            acc[nt] = __builtin_amdgcn_mfma_f32_16x16x32_bf16(a, b, acc[nt], 0, 0, 0);
        }
    }

#pragma unroll
    for (int nt = 0; nt < 25; ++nt) {
        const int col = nt * 16 + ln;
        const float bias = lstm_b[col];
#pragma unroll
        for (int j = 0; j < 4; ++j) {
            const int row = m0 + qd * 4 + j;
            xpart[(size_t)row * 400 + col] = acc[nt][j] + bias;
        }
    }
}

// ---------------------------------------------------------------------------
// Kernel 2: LSTM recurrence + att2 pooling + dense, fused per batch row.
// grid = B blocks, 448 threads (400 active in recurrence).
// h history kept in LDS (no lstm global round-trip).
// ---------------------------------------------------------------------------
__global__ __launch_bounds__(448) void lstm_att2_kernel(
    const float* __restrict__ xpart,     // [2048][400] (bias included)
    const float* __restrict__ lstm_W,    // [200][400]
    const float* __restrict__ att2_mat,  // [H,H]
    const float* __restrict__ att2_bias, // [H]
    const float* __restrict__ att2_vec,  // [H]
    const float* __restrict__ dense_w,   // [H]
    const float* __restrict__ dense_b,   // [1]
    float* __restrict__ out)             // [B]
{
    __shared__ __align__(16) float h_s[Hsz];
    __shared__ float z_s[400];
    __shared__ __align__(16) float hist[Esz][Hsz];   // 25.6 KB
    __shared__ float w2_s[Esz * Hsz];                // 25.6 KB
    __shared__ float u2_s[Esz];
    __shared__ float alpha2_s[Esz];
    __shared__ float repr_s[Hsz];

    const int b = blockIdx.x;
    const int tid = threadIdx.x;
    const bool actv = tid < 400;

    float w[100];
    if (actv) {
#pragma unroll
        for (int k = 0; k < 100; ++k) w[k] = lstm_W[(size_t)(Fsz + k) * 400 + tid];
    }
    float c = 0.f;
    if (tid < Hsz) h_s[tid] = 0.f;
    __syncthreads();

    float xp_cur = actv ? xpart[(size_t)b * Esz * 400 + tid] : 0.f;
    const float4* h4 = reinterpret_cast<const float4*>(h_s);

    for (int t = 0; t < Esz; ++t) {
        const float xp_next = (actv && (t + 1) < Esz)
            ? xpart[((size_t)b * Esz + t + 1) * 400 + tid] : 0.f;
        if (actv) {
            float z0 = xp_cur, z1 = 0.f, z2 = 0.f, z3 = 0.f;
#pragma unroll
            for (int k4 = 0; k4 < 25; ++k4) {
                const float4 hv = h4[k4];
                z0 += hv.x * w[4 * k4 + 0];
                z1 += hv.y * w[4 * k4 + 1];
                z2 += hv.z * w[4 * k4 + 2];
                z3 += hv.w * w[4 * k4 + 3];
            }
            z_s[tid] = (z0 + z1) + (z2 + z3);
        }
        __syncthreads();

        if (tid < Hsz) {
            const float zi = z_s[tid];
            const float zj = z_s[tid + 100];
            const float zf = z_s[tid + 200];
            const float zo = z_s[tid + 300];
            c = c * sigmoid_fast(zf + 1.0f) + sigmoid_fast(zi) * tanhf_fast(zj);
            const float h = sigmoid_fast(zo) * tanhf_fast(c);
            h_s[tid] = h;
            hist[t][tid] = h;
        }
        __syncthreads();
        xp_cur = xp_next;
    }

    // ---- att2 on hist ----
    for (int idx = tid; idx < Esz * Hsz; idx += 448) {
        const int e = idx / Hsz;
        const int g = idx - e * Hsz;
        const float* lp = hist[e];
        float a0 = 0.f, a1 = 0.f, a2 = 0.f, a3 = 0.f;
        for (int k = 0; k < Hsz; k += 4) {
            a0 += lp[k + 0] * att2_mat[(k + 0) * Hsz + g];
            a1 += lp[k + 1] * att2_mat[(k + 1) * Hsz + g];
            a2 += lp[k + 2] * att2_mat[(k + 2) * Hsz + g];
            a3 += lp[k + 3] * att2_mat[(k + 3) * Hsz + g];
        }
        w2_s[idx] = tanhf_fast(att2_bias[g] + ((a0 + a1) + (a2 + a3))) * att2_vec[g];
    }
    __syncthreads();

    if (tid < Esz) {
        float acc = 0.f;
        const float* wp = w2_s + tid * Hsz;
        for (int g = 0; g < Hsz; ++g) acc += wp[g];
        u2_s[tid] = acc;
    }
    __syncthreads();

    if (tid < 64) {
        const float uv = u2_s[tid];
        float m = uv;
#pragma unroll
        for (int off = 32; off > 0; off >>= 1) m = fmaxf(m, __shfl_xor(m, off));
        float e = __expf(uv - m);
        float sum = e;
#pragma unroll
        for (int off = 32; off > 0; off >>= 1) sum += __shfl_xor(sum, off);
        alpha2_s[tid] = e / sum;
    }
    __syncthreads();

    if (tid < Hsz) {
        float acc = 0.f;
        for (int e = 0; e < Esz; ++e) acc += alpha2_s[e] * hist[e][tid];
        repr_s[tid] = acc;
    }
    __syncthreads();

    if (tid == 0) {
        float acc = dense_b[0];
        for (int hh = 0; hh < Hsz; ++hh) acc += repr_s[hh] * dense_w[hh];
        out[b] = sigmoid_fast(acc);
    }
}

// ---------------------------------------------------------------------------
extern "C" void kernel_launch(void* const* d_in, const int* in_sizes, int n_in,
                              void* d_out, int out_size, void* d_ws, size_t ws_size,
                              hipStream_t stream) {
    const float* essays    = (const float*)d_in[0];
    const float* conv_k    = (const float*)d_in[1];
    const float* conv_b    = (const float*)d_in[2];
    const float* att1_mat  = (const float*)d_in[3];
    const float* att1_bias = (const float*)d_in[4];
    const float* att1_vec  = (const float*)d_in[5];
    const float* lstm_W    = (const float*)d_in[6];
    const float* lstm_b    = (const float*)d_in[7];
    const float* att2_mat  = (const float*)d_in[8];
    const float* att2_bias = (const float*)d_in[9];
    const float* att2_vec  = (const float*)d_in[10];
    const float* dense_w   = (const float*)d_in[11];
    const float* dense_b   = (const float*)d_in[12];

    float* out = (float*)d_out;

    // workspace layout (256B-aligned chunks)
    char* ws = (char*)d_ws;
    unsigned short* sent_bf = (unsigned short*)ws;              // 524288 B
    float* xpart = (float*)(ws + 524288);                       // 3276800 B
    unsigned short* BtgC = (unsigned short*)(ws + 3801088);     // 358400 B
    unsigned short* BtgA = (unsigned short*)(ws + 4159488);     // 28672 B
    unsigned short* BtgW = (unsigned short*)(ws + 4188160);     // 102400 B

    prep_kernel<<<512, 256, 0, stream>>>(conv_k, att1_mat, lstm_W, BtgC, BtgA, BtgW);
    conv_att1_kernel<<<Bsz * Esz, 256, 0, stream>>>(
        essays, BtgC, BtgA, conv_b, att1_bias, att1_vec, sent_bf);
    xpart_kernel<<<32, 256, 0, stream>>>(sent_bf, BtgW, lstm_b, xpart);
    lstm_att2_kernel<<<Bsz, 448, 0, stream>>>(
        xpart, lstm_W, att2_mat, att2_bias, att2_vec, dense_w, dense_b, out);
}

// Round 6
// 208.929 us; speedup vs baseline: 23.3726x; 1.0129x over previous
//
#include <hip/hip_runtime.h>
#include <hip/hip_bf16.h>
#include <stdint.h>

// Problem constants
#define Bsz 32
#define Esz 64
#define Ssz 50
#define Dsz 300
#define Fsz 100
#define Hsz 100
#define WWIN 5

// Conv-as-GEMM geometry (per (b,e) block)
#define PX   328          // Xp row pitch in bf16 elems
#define PC   136          // conv_bf row pitch in bf16 elems
#define KT_CONV 50        // K' = 5 windows * 320 = 1600 -> 50 k-tiles of 32
#define NTILES  7         // N = 112 (100 padded)
#define MTILES  4         // M = 64  (50 padded)
#define NGRP 2214         // 54 rows * 41 groups-of-8

typedef __attribute__((ext_vector_type(8))) short bf16x8;
typedef __attribute__((ext_vector_type(8))) unsigned short u16x8;
typedef __attribute__((ext_vector_type(4))) float f32x4;

__device__ __forceinline__ float sigmoid_fast(float x) {
    return 1.0f / (1.0f + __expf(-x));
}
__device__ __forceinline__ float tanhf_fast(float x) {
    const float ax = fabsf(x);
    const float e = __expf(2.0f * ax);
    const float t = 1.0f - 2.0f / (e + 1.0f);
    return copysignf(t, x);
}

__device__ __forceinline__ unsigned short f2bf(float x) {
    union { __hip_bfloat16 h; unsigned short u; } cv;
    cv.h = __float2bfloat16(x);
    return cv.u;
}
__device__ __forceinline__ unsigned int f2bf2(float lo, float hi) {
    union { __hip_bfloat162 h2; unsigned int u; } cv;
    cv.h2 = __float22bfloat162_rn(make_float2(lo, hi));
    return cv.u;
}
__device__ __forceinline__ float bf2f(unsigned short b) {
    union { uint32_t u; float f; } v; v.u = ((uint32_t)b) << 16;
    return v.f;
}

// ---------------------------------------------------------------------------
// Prep kernel: bf16 MFMA B-operands.
//  BtgC: [50][112][32] bf16   conv_k padded (d->320 per window, f->112)
//  BtgA: [4][112][32]  bf16   att1_mat padded (k->128, g->112)
//  BtgW: [4][400][32]  bf16   lstm_W x-part rows 0..99 padded (k->128), n=400
// ---------------------------------------------------------------------------
#define N_BTGC (KT_CONV * 112 * 32)   // 179200
#define N_BTGA (4 * 112 * 32)         // 14336
#define N_BTGW (4 * 400 * 32)         // 51200

__global__ __launch_bounds__(256) void prep_kernel(
    const float* __restrict__ conv_k, const float* __restrict__ att1_mat,
    const float* __restrict__ lstm_W,
    unsigned short* __restrict__ BtgC, unsigned short* __restrict__ BtgA,
    unsigned short* __restrict__ BtgW)
{
    const int total = N_BTGC + N_BTGA + N_BTGW;
    for (int i = blockIdx.x * 256 + threadIdx.x; i < total; i += gridDim.x * 256) {
        if (i < N_BTGC) {
            const int kt = i / (112 * 32);
            const int r  = i % (112 * 32);
            const int n  = r / 32;
            const int kk = r % 32;
            const int w  = kt / 10;
            const int d  = (kt % 10) * 32 + kk;
            float val = (d < Dsz && n < Fsz) ? conv_k[((size_t)w * Dsz + d) * Fsz + n] : 0.f;
            BtgC[i] = f2bf(val);
        } else if (i < N_BTGC + N_BTGA) {
            const int j  = i - N_BTGC;
            const int kt = j / (112 * 32);
            const int r  = j % (112 * 32);
            const int n  = r / 32;
            const int kk = r % 32;
            const int k  = kt * 32 + kk;
            float val = (k < Fsz && n < Fsz) ? att1_mat[(size_t)k * Fsz + n] : 0.f;
            BtgA[j] = f2bf(val);
        } else {
            const int j  = i - N_BTGC - N_BTGA;
            const int kt = j / (400 * 32);
            const int r  = j % (400 * 32);
            const int n  = r / 32;
            const int kk = r % 32;
            const int k  = kt * 32 + kk;
            float val = (k < Fsz) ? lstm_W[(size_t)k * 400 + n] : 0.f;
            BtgW[j] = f2bf(val);
        }
    }
}

// ---------------------------------------------------------------------------
// Conv K-loop helpers: compile-time kt group indices, register B pipeline.
// B fragments are shared across BOTH essays (8 m-tiles per B load).
// ---------------------------------------------------------------------------
template<int G>
__device__ __forceinline__ void conv_loadB(
    const unsigned short* __restrict__ BtgC, int boff0, int boff1, bool has1,
    bf16x8 (&bR)[5][2])
{
#pragma unroll
    for (int i = 0; i < 5; ++i) {
        const int kt = G * 5 + i;
        bR[i][0] = *reinterpret_cast<const bf16x8*>(BtgC + kt * 3584 + boff0);
        bR[i][1] = has1 ? *reinterpret_cast<const bf16x8*>(BtgC + kt * 3584 + boff1)
                        : (bf16x8)0;
    }
}

template<int G>
__device__ __forceinline__ void conv_compute(
    const unsigned short* buf0, const unsigned short* buf1,
    const int (&abase)[MTILES], bool has1,
    const bf16x8 (&bR)[5][2], f32x4 (&acc)[2][MTILES][2])
{
#pragma unroll
    for (int i = 0; i < 5; ++i) {
        const int kt  = G * 5 + i;
        const int w   = kt / 10;
        const int t   = kt % 10;
        const int off = w * PX + t * 32;   // compile-time immediate
#pragma unroll
        for (int mt = 0; mt < MTILES; ++mt) {
            const bf16x8 af0 = *reinterpret_cast<const bf16x8*>(&buf0[abase[mt] + off]);
            const bf16x8 af1 = *reinterpret_cast<const bf16x8*>(&buf1[abase[mt] + off]);
            acc[0][mt][0] = __builtin_amdgcn_mfma_f32_16x16x32_bf16(af0, bR[i][0], acc[0][mt][0], 0, 0, 0);
            acc[1][mt][0] = __builtin_amdgcn_mfma_f32_16x16x32_bf16(af1, bR[i][0], acc[1][mt][0], 0, 0, 0);
            if (has1) {
                acc[0][mt][1] = __builtin_amdgcn_mfma_f32_16x16x32_bf16(af0, bR[i][1], acc[0][mt][1], 0, 0, 0);
                acc[1][mt][1] = __builtin_amdgcn_mfma_f32_16x16x32_bf16(af1, bR[i][1], acc[1][mt][1], 0, 0, 0);
            }
        }
    }
}

// ---------------------------------------------------------------------------
// Kernel 1: TWO essays per block. conv via bf16 MFMA + att1 pooling.
// grid = B*E/2 blocks, 256 threads (4 waves). Waves split N-tiles.
// ---------------------------------------------------------------------------
__global__ __launch_bounds__(256, 2) void conv_att1_kernel(
    const float* __restrict__ essays,       // [B,E,S,D]
    const unsigned short* __restrict__ BtgC,// [50][112][32] bf16
    const unsigned short* __restrict__ BtgA,// [4][112][32] bf16
    const float* __restrict__ conv_b,       // [F]
    const float* __restrict__ att1_bias,    // [F]
    const float* __restrict__ att1_vec,     // [F]
    unsigned short* __restrict__ sent_bf)   // [2048][128] bf16 (cols 100..127 = 0)
{
    __shared__ __align__(16) unsigned short buf[2][54 * PX];   // 70848 B
    __shared__ float u_s[2][64];
    __shared__ float alpha_s[2][64];

    const int be0 = blockIdx.x * 2;
    const int tid = threadIdx.x;
    const int lane = tid & 63;
    const int wid  = tid >> 6;           // 0..3
    const int ln   = lane & 15;
    const int qd   = lane >> 4;          // 0..3

    if (tid < 128) u_s[tid >> 6][tid & 63] = 0.f;

    // ---- stage Xp for both essays (bf16, zero-padded) ----
#pragma unroll
    for (int es = 0; es < 2; ++es) {
        const float* in_g = essays + (size_t)(be0 + es) * (Ssz * Dsz);
        float4 va[9], vb[9];
        int rr[9], cc[9];
        bool hv[9], fv[9], gv[9];
#pragma unroll
        for (int it = 0; it < 9; ++it) {
            const int g  = tid + it * 256;
            const int r  = g / 41;
            const int c8 = (g - r * 41) * 8;
            const int s  = r - 2;
            gv[it] = (g < NGRP);
            hv[it] = gv[it] && (s >= 0) && (s < Ssz) && (c8 < Dsz);
            fv[it] = hv[it] && (c8 + 8 <= Dsz);
            const float* base = in_g + (hv[it] ? (s * Dsz + c8) : 0);
            va[it] = *reinterpret_cast<const float4*>(base);
            vb[it] = *reinterpret_cast<const float4*>(fv[it] ? base + 4 : base);
            rr[it] = r; cc[it] = c8;
        }
#pragma unroll
        for (int it = 0; it < 9; ++it) {
            if (!gv[it]) continue;
            const float e0 = hv[it] ? va[it].x : 0.f;
            const float e1 = hv[it] ? va[it].y : 0.f;
            const float e2 = hv[it] ? va[it].z : 0.f;
            const float e3 = hv[it] ? va[it].w : 0.f;
            const float e4 = fv[it] ? vb[it].x : 0.f;
            const float e5 = fv[it] ? vb[it].y : 0.f;
            const float e6 = fv[it] ? vb[it].z : 0.f;
            const float e7 = fv[it] ? vb[it].w : 0.f;
            uint4 o;
            o.x = f2bf2(e0, e1);
            o.y = f2bf2(e2, e3);
            o.z = f2bf2(e4, e5);
            o.w = f2bf2(e6, e7);
            *reinterpret_cast<uint4*>(&buf[es][rr[it] * PX + cc[it]]) = o;
        }
    }
    __syncthreads();

    // ---- conv MFMA: M=2x64, N=112, K'=1600. wave wid owns nt0=wid, nt1=wid+4 ----
    const int nt0 = wid;
    const int nt1 = wid + 4;
    const bool has1 = (nt1 < NTILES);
    const int boff0 = (nt0 * 16 + ln) * 32 + 8 * qd;
    const int boff1 = (nt1 * 16 + ln) * 32 + 8 * qd;

    int abase[MTILES];
#pragma unroll
    for (int mt = 0; mt < MTILES; ++mt) {
        const int m = mt * 16 + ln;
        abase[mt] = (m < Ssz ? m : Ssz - 1) * PX + 8 * qd;
    }

    f32x4 acc[2][MTILES][2];
#pragma unroll
    for (int es = 0; es < 2; ++es)
#pragma unroll
        for (int mt = 0; mt < MTILES; ++mt) { acc[es][mt][0] = (f32x4)0.f; acc[es][mt][1] = (f32x4)0.f; }

    {
        const unsigned short* b0p = buf[0];
        const unsigned short* b1p = buf[1];
        bf16x8 bX[5][2], bY[5][2];
        conv_loadB<0>(BtgC, boff0, boff1, has1, bX);
        conv_loadB<1>(BtgC, boff0, boff1, has1, bY);
        conv_compute<0>(b0p, b1p, abase, has1, bX, acc);
        conv_loadB<2>(BtgC, boff0, boff1, has1, bX);
        conv_compute<1>(b0p, b1p, abase, has1, bY, acc);
        conv_loadB<3>(BtgC, boff0, boff1, has1, bY);
        conv_compute<2>(b0p, b1p, abase, has1, bX, acc);
        conv_loadB<4>(BtgC, boff0, boff1, has1, bX);
        conv_compute<3>(b0p, b1p, abase, has1, bY, acc);
        conv_loadB<5>(BtgC, boff0, boff1, has1, bY);
        conv_compute<4>(b0p, b1p, abase, has1, bX, acc);
        conv_loadB<6>(BtgC, boff0, boff1, has1, bX);
        conv_compute<5>(b0p, b1p, abase, has1, bY, acc);
        conv_loadB<7>(BtgC, boff0, boff1, has1, bY);
        conv_compute<6>(b0p, b1p, abase, has1, bX, acc);
        conv_loadB<8>(BtgC, boff0, boff1, has1, bX);
        conv_compute<7>(b0p, b1p, abase, has1, bY, acc);
        conv_loadB<9>(BtgC, boff0, boff1, has1, bY);
        conv_compute<8>(b0p, b1p, abase, has1, bX, acc);
        conv_compute<9>(b0p, b1p, abase, has1, bY, acc);
    }

    // issue att1 B loads early (global, independent of LDS overlay)
    bf16x8 a1b[4][2];
#pragma unroll
    for (int kt = 0; kt < 4; ++kt) {
        a1b[kt][0] = *reinterpret_cast<const bf16x8*>(BtgA + kt * 3584 + boff0);
        a1b[kt][1] = has1 ? *reinterpret_cast<const bf16x8*>(BtgA + kt * 3584 + boff1)
                          : (bf16x8)0;
    }
    __syncthreads();   // Xp dead from here; convbf overlays buf

    // ---- epilogue: bias + relu -> convbf (bf16, overlaid at buf[es]) ----
    {
        const float bias0 = conv_b[nt0 * 16 + ln];    // nt0*16+ln < 100 always
        const int n_g1 = nt1 * 16 + ln;
        const bool g1ok = has1 && (n_g1 < Fsz);
        const float bias1 = g1ok ? conv_b[n_g1] : 0.f;
#pragma unroll
        for (int es = 0; es < 2; ++es) {
#pragma unroll
            for (int mt = 0; mt < MTILES; ++mt) {
#pragma unroll
                for (int j = 0; j < 4; ++j) {
                    const int m_row = mt * 16 + qd * 4 + j;
                    buf[es][m_row * PC + nt0 * 16 + ln] = f2bf(fmaxf(acc[es][mt][0][j] + bias0, 0.f));
                    if (g1ok)
                        buf[es][m_row * PC + n_g1] = f2bf(fmaxf(acc[es][mt][1][j] + bias1, 0.f));
                }
            }
        }
    }
    // zero K-pad cols 112..127 of convbf (att1 MFMA reads K up to 128)
    for (int idx = tid; idx < 2 * 64 * 2; idx += 256) {
        const int es = idx >> 7;
        const int r2 = idx & 127;
        const int row = r2 >> 1;
        const int c = 112 + (r2 & 1) * 8;
        *reinterpret_cast<u16x8*>(&buf[es][row * PC + c]) = (u16x8)0;
    }
    __syncthreads();

    // ---- att1 scores MFMA + in-register reduction over g ----
    f32x4 acc2[2][MTILES][2];
#pragma unroll
    for (int es = 0; es < 2; ++es)
#pragma unroll
        for (int mt = 0; mt < MTILES; ++mt) { acc2[es][mt][0] = (f32x4)0.f; acc2[es][mt][1] = (f32x4)0.f; }

#pragma unroll
    for (int kt = 0; kt < 4; ++kt) {
#pragma unroll
        for (int es = 0; es < 2; ++es) {
#pragma unroll
            for (int mt = 0; mt < MTILES; ++mt) {
                const bf16x8 af = *reinterpret_cast<const bf16x8*>(
                    &buf[es][(mt * 16 + ln) * PC + kt * 32 + 8 * qd]);
                acc2[es][mt][0] = __builtin_amdgcn_mfma_f32_16x16x32_bf16(af, a1b[kt][0], acc2[es][mt][0], 0, 0, 0);
                if (has1)
                    acc2[es][mt][1] = __builtin_amdgcn_mfma_f32_16x16x32_bf16(af, a1b[kt][1], acc2[es][mt][1], 0, 0, 0);
            }
        }
    }

    // scores: tanh(acc2+bias)*vec; combine both n-tiles, reduce 16 ln-lanes, atomic
    {
        const int g0 = nt0 * 16 + ln;                 // always < 100
        const float b1v0 = att1_bias[g0];
        const float vv0  = att1_vec[g0];
        const int g1 = nt1 * 16 + ln;
        const bool g1v = has1 && (g1 < Fsz);
        const float b1v1 = g1v ? att1_bias[g1] : 0.f;
        const float vv1  = g1v ? att1_vec[g1]  : 0.f;
#pragma unroll
        for (int es = 0; es < 2; ++es) {
#pragma unroll
            for (int mt = 0; mt < MTILES; ++mt) {
#pragma unroll
                for (int j = 0; j < 4; ++j) {
                    const int m_row = mt * 16 + qd * 4 + j;
                    float val = 0.f;
                    if (m_row < Ssz) {
                        val = tanhf_fast(acc2[es][mt][0][j] + b1v0) * vv0;
                        if (g1v) val += tanhf_fast(acc2[es][mt][1][j] + b1v1) * vv1;
                    }
                    val += __shfl_xor(val, 1);
                    val += __shfl_xor(val, 2);
                    val += __shfl_xor(val, 4);
                    val += __shfl_xor(val, 8);
                    if (ln == 0 && m_row < Ssz) atomicAdd(&u_s[es][m_row], val);
                }
            }
        }
    }
    __syncthreads();

    // ---- softmax over s (waves 0 and 1, one essay each) ----
    if (wid < 2) {
        const float uv = (lane < Ssz) ? u_s[wid][lane] : -1e30f;
        float m = uv;
#pragma unroll
        for (int off = 32; off > 0; off >>= 1) m = fmaxf(m, __shfl_xor(m, off));
        float e = (lane < Ssz) ? __expf(uv - m) : 0.f;
        float sum = e;
#pragma unroll
        for (int off = 32; off > 0; off >>= 1) sum += __shfl_xor(sum, off);
        alpha_s[wid][lane] = e / sum;
    }
    __syncthreads();

    // ---- sent_bf: all 256 threads (es = tid>>7, col = tid&127) ----
    {
        const int es = tid >> 7;
        const int f  = tid & 127;
        unsigned short v = 0;
        if (f < Fsz) {
            float a = 0.f;
            for (int s = 0; s < Ssz; ++s) a += alpha_s[es][s] * bf2f(buf[es][s * PC + f]);
            v = f2bf(a);
        }
        sent_bf[(size_t)(be0 + es) * 128 + f] = v;
    }
}

// ---------------------------------------------------------------------------
// Kernel 1b: xpart = sent_bf @ Wx + lstm_b  -> [2048][400] fp32
// grid = 32 blocks x 256 threads; wave w handles M-tile blockIdx*4+w
// ---------------------------------------------------------------------------
__global__ __launch_bounds__(256) void xpart_kernel(
    const unsigned short* __restrict__ sent_bf, // [2048][128]
    const unsigned short* __restrict__ BtgW,    // [4][400][32]
    const float* __restrict__ lstm_b,           // [400]
    float* __restrict__ xpart)                  // [2048][400]
{
    const int wid  = threadIdx.x >> 6;
    const int mt   = blockIdx.x * 4 + wid;      // 0..127
    const int lane = threadIdx.x & 63;
    const int ln   = lane & 15;
    const int qd   = lane >> 4;
    const int m0   = mt * 16;

    f32x4 acc[25];
#pragma unroll
    for (int nt = 0; nt < 25; ++nt) acc[nt] = (f32x4)0.f;

#pragma unroll
    for (int kt = 0; kt < 4; ++kt) {
        const bf16x8 a = *reinterpret_cast<const bf16x8*>(
            sent_bf + (size_t)(m0 + ln) * 128 + kt * 32 + 8 * qd);
#pragma unroll
        for (int nt = 0; nt < 25; ++nt) {
            const bf16x8 b = *reinterpret_cast<const bf16x8*>(
                BtgW + ((size_t)kt * 400 + nt * 16 + ln) * 32 + 8 * qd);
            acc[nt] = __builtin_amdgcn_mfma_f32_16x16x32_bf16(a, b, acc[nt], 0, 0, 0);
        }
    }

#pragma unroll
    for (int nt = 0; nt < 25; ++nt) {
        const int col = nt * 16 + ln;
        const float bias = lstm_b[col];
#pragma unroll
        for (int j = 0; j < 4; ++j) {
            const int row = m0 + qd * 4 + j;
            xpart[(size_t)row * 400 + col] = acc[nt][j] + bias;
        }
    }
}

// ---------------------------------------------------------------------------
// Kernel 2: LSTM recurrence + att2 pooling + dense, fused per batch row.
// grid = B blocks, 448 threads (400 active in recurrence).
// ---------------------------------------------------------------------------
__global__ __launch_bounds__(448) void lstm_att2_kernel(
    const float* __restrict__ xpart,     // [2048][400] (bias included)
    const float* __restrict__ lstm_W,    // [200][400]
    const float* __restrict__ att2_mat,  // [H,H]
    const float* __restrict__ att2_bias, // [H]
    const float* __restrict__ att2_vec,  // [H]
    const float* __restrict__ dense_w,   // [H]
    const float* __restrict__ dense_b,   // [1]
    float* __restrict__ out)             // [B]
{
    __shared__ __align__(16) float h_s[Hsz];
    __shared__ float z_s[400];
    __shared__ __align__(16) float hist[Esz][Hsz];   // 25.6 KB
    __shared__ float w2_s[Esz * Hsz];                // 25.6 KB
    __shared__ float u2_s[Esz];
    __shared__ float alpha2_s[Esz];
    __shared__ float repr_s[Hsz];

    const int b = blockIdx.x;
    const int tid = threadIdx.x;
    const bool actv = tid < 400;

    float w[100];
    if (actv) {
#pragma unroll
        for (int k = 0; k < 100; ++k) w[k] = lstm_W[(size_t)(Fsz + k) * 400 + tid];
    }
    float c = 0.f;
    if (tid < Hsz) h_s[tid] = 0.f;
    __syncthreads();

    float xp_cur = actv ? xpart[(size_t)b * Esz * 400 + tid] : 0.f;
    const float4* h4 = reinterpret_cast<const float4*>(h_s);

    for (int t = 0; t < Esz; ++t) {
        const float xp_next = (actv && (t + 1) < Esz)
            ? xpart[((size_t)b * Esz + t + 1) * 400 + tid] : 0.f;
        if (actv) {
            float z0 = xp_cur, z1 = 0.f, z2 = 0.f, z3 = 0.f;
#pragma unroll
            for (int k4 = 0; k4 < 25; ++k4) {
                const float4 hv = h4[k4];
                z0 += hv.x * w[4 * k4 + 0];
                z1 += hv.y * w[4 * k4 + 1];
                z2 += hv.z * w[4 * k4 + 2];
                z3 += hv.w * w[4 * k4 + 3];
            }
            z_s[tid] = (z0 + z1) + (z2 + z3);
        }
        __syncthreads();

        if (tid < Hsz) {
            const float zi = z_s[tid];
            const float zj = z_s[tid + 100];
            const float zf = z_s[tid + 200];
            const float zo = z_s[tid + 300];
            c = c * sigmoid_fast(zf + 1.0f) + sigmoid_fast(zi) * tanhf_fast(zj);
            const float h = sigmoid_fast(zo) * tanhf_fast(c);
            h_s[tid] = h;
            hist[t][tid] = h;
        }
        __syncthreads();
        xp_cur = xp_next;
    }

    // ---- att2 on hist ----
    for (int idx = tid; idx < Esz * Hsz; idx += 448) {
        const int e = idx / Hsz;
        const int g = idx - e * Hsz;
        const float* lp = hist[e];
        float a0 = 0.f, a1 = 0.f, a2 = 0.f, a3 = 0.f;
        for (int k = 0; k < Hsz; k += 4) {
            a0 += lp[k + 0] * att2_mat[(k + 0) * Hsz + g];
            a1 += lp[k + 1] * att2_mat[(k + 1) * Hsz + g];
            a2 += lp[k + 2] * att2_mat[(k + 2) * Hsz + g];
            a3 += lp[k + 3] * att2_mat[(k + 3) * Hsz + g];
        }
        w2_s[idx] = tanhf_fast(att2_bias[g] + ((a0 + a1) + (a2 + a3))) * att2_vec[g];
    }
    __syncthreads();

    if (tid < Esz) {
        float acc = 0.f;
        const float* wp = w2_s + tid * Hsz;
        for (int g = 0; g < Hsz; ++g) acc += wp[g];
        u2_s[tid] = acc;
    }
    __syncthreads();

    if (tid < 64) {
        const float uv = u2_s[tid];
        float m = uv;
#pragma unroll
        for (int off = 32; off > 0; off >>= 1) m = fmaxf(m, __shfl_xor(m, off));
        float e = __expf(uv - m);
        float sum = e;
#pragma unroll
        for (int off = 32; off > 0; off >>= 1) sum += __shfl_xor(sum, off);
        alpha2_s[tid] = e / sum;
    }
    __syncthreads();

    if (tid < Hsz) {
        float acc = 0.f;
        for (int e = 0; e < Esz; ++e) acc += alpha2_s[e] * hist[e][tid];
        repr_s[tid] = acc;
    }
    __syncthreads();

    if (tid == 0) {
        float acc = dense_b[0];
        for (int hh = 0; hh < Hsz; ++hh) acc += repr_s[hh] * dense_w[hh];
        out[b] = sigmoid_fast(acc);
    }
}

// ---------------------------------------------------------------------------
extern "C" void kernel_launch(void* const* d_in, const int* in_sizes, int n_in,
                              void* d_out, int out_size, void* d_ws, size_t ws_size,
                              hipStream_t stream) {
    const float* essays    = (const float*)d_in[0];
    const float* conv_k    = (const float*)d_in[1];
    const float* conv_b    = (const float*)d_in[2];
    const float* att1_mat  = (const float*)d_in[3];
    const float* att1_bias = (const float*)d_in[4];
    const float* att1_vec  = (const float*)d_in[5];
    const float* lstm_W    = (const float*)d_in[6];
    const float* lstm_b    = (const float*)d_in[7];
    const float* att2_mat  = (const float*)d_in[8];
    const float* att2_bias = (const float*)d_in[9];
    const float* att2_vec  = (const float*)d_in[10];
    const float* dense_w   = (const float*)d_in[11];
    const float* dense_b   = (const float*)d_in[12];

    float* out = (float*)d_out;

    // workspace layout (256B-aligned chunks)
    char* ws = (char*)d_ws;
    unsigned short* sent_bf = (unsigned short*)ws;              // 524288 B
    float* xpart = (float*)(ws + 524288);                       // 3276800 B
    unsigned short* BtgC = (unsigned short*)(ws + 3801088);     // 358400 B
    unsigned short* BtgA = (unsigned short*)(ws + 4159488);     // 28672 B
    unsigned short* BtgW = (unsigned short*)(ws + 4188160);     // 102400 B

    prep_kernel<<<512, 256, 0, stream>>>(conv_k, att1_mat, lstm_W, BtgC, BtgA, BtgW);
    conv_att1_kernel<<<Bsz * Esz / 2, 256, 0, stream>>>(
        essays, BtgC, BtgA, conv_b, att1_bias, att1_vec, sent_bf);
    xpart_kernel<<<32, 256, 0, stream>>>(sent_bf, BtgW, lstm_b, xpart);
    lstm_att2_kernel<<<Bsz, 448, 0, stream>>>(
        xpart, lstm_W, att2_mat, att2_bias, att2_vec, dense_w, dense_b, out);
}

// Round 7
// 202.765 us; speedup vs baseline: 24.0832x; 1.0304x over previous
//
#include <hip/hip_runtime.h>
#include <hip/hip_bf16.h>
#include <stdint.h>

// Problem constants
#define Bsz 32
#define Esz 64
#define Ssz 50
#define Dsz 300
#define Fsz 100
#define Hsz 100
#define WWIN 5

// Conv-as-GEMM geometry (per (b,e) block)
#define PX   328          // Xp row pitch in bf16 elems
#define PC   136          // conv_bf row pitch in bf16 elems
#define KT_CONV 50        // K' = 5 windows * 320 = 1600 -> 50 k-tiles of 32
#define NTILES  7         // N = 112 (100 padded)
#define MTILES  4         // M = 64  (50 padded)
#define NGRP 2214         // 54 rows * 41 groups-of-8

typedef __attribute__((ext_vector_type(8))) short bf16x8;
typedef __attribute__((ext_vector_type(8))) unsigned short u16x8;
typedef __attribute__((ext_vector_type(4))) float f32x4;

__device__ __forceinline__ float sigmoid_fast(float x) {
    return 1.0f / (1.0f + __expf(-x));
}
__device__ __forceinline__ float tanhf_fast(float x) {
    const float ax = fabsf(x);
    const float e = __expf(2.0f * ax);
    const float t = 1.0f - 2.0f / (e + 1.0f);
    return copysignf(t, x);
}

__device__ __forceinline__ unsigned short f2bf(float x) {
    union { __hip_bfloat16 h; unsigned short u; } cv;
    cv.h = __float2bfloat16(x);
    return cv.u;
}
__device__ __forceinline__ unsigned int f2bf2(float lo, float hi) {
    union { __hip_bfloat162 h2; unsigned int u; } cv;
    cv.h2 = __float22bfloat162_rn(make_float2(lo, hi));
    return cv.u;
}
__device__ __forceinline__ float bf2f(unsigned short b) {
    union { uint32_t u; float f; } v; v.u = ((uint32_t)b) << 16;
    return v.f;
}

// ---------------------------------------------------------------------------
// Prep kernel: bf16 MFMA B-operands.
//  BtgC: [50][112][32] bf16   conv_k padded (d->320 per window, f->112)
//  BtgA: [4][112][32]  bf16   att1_mat padded (k->128, g->112)
//  BtgW: [4][400][32]  bf16   lstm_W x-part rows 0..99 padded (k->128), n=400
// ---------------------------------------------------------------------------
#define N_BTGC (KT_CONV * 112 * 32)   // 179200
#define N_BTGA (4 * 112 * 32)         // 14336
#define N_BTGW (4 * 400 * 32)         // 51200

__global__ __launch_bounds__(256) void prep_kernel(
    const float* __restrict__ conv_k, const float* __restrict__ att1_mat,
    const float* __restrict__ lstm_W,
    unsigned short* __restrict__ BtgC, unsigned short* __restrict__ BtgA,
    unsigned short* __restrict__ BtgW)
{
    const int total = N_BTGC + N_BTGA + N_BTGW;
    for (int i = blockIdx.x * 256 + threadIdx.x; i < total; i += gridDim.x * 256) {
        if (i < N_BTGC) {
            const int kt = i / (112 * 32);
            const int r  = i % (112 * 32);
            const int n  = r / 32;
            const int kk = r % 32;
            const int w  = kt / 10;
            const int d  = (kt % 10) * 32 + kk;
            float val = (d < Dsz && n < Fsz) ? conv_k[((size_t)w * Dsz + d) * Fsz + n] : 0.f;
            BtgC[i] = f2bf(val);
        } else if (i < N_BTGC + N_BTGA) {
            const int j  = i - N_BTGC;
            const int kt = j / (112 * 32);
            const int r  = j % (112 * 32);
            const int n  = r / 32;
            const int kk = r % 32;
            const int k  = kt * 32 + kk;
            float val = (k < Fsz && n < Fsz) ? att1_mat[(size_t)k * Fsz + n] : 0.f;
            BtgA[j] = f2bf(val);
        } else {
            const int j  = i - N_BTGC - N_BTGA;
            const int kt = j / (400 * 32);
            const int r  = j % (400 * 32);
            const int n  = r / 32;
            const int kk = r % 32;
            const int k  = kt * 32 + kk;
            float val = (k < Fsz) ? lstm_W[(size_t)k * 400 + n] : 0.f;
            BtgW[j] = f2bf(val);
        }
    }
}

// ---------------------------------------------------------------------------
// Conv K-loop helpers: compile-time offsets, register pipelines for A and B.
// ---------------------------------------------------------------------------
template<int G>
__device__ __forceinline__ void conv_loadB(
    const unsigned short* __restrict__ BtgC, int boff0, int boff1, bool has1,
    bf16x8 (&bR)[5][2])
{
#pragma unroll
    for (int i = 0; i < 5; ++i) {
        const int kt = G * 5 + i;
        bR[i][0] = *reinterpret_cast<const bf16x8*>(BtgC + kt * 3584 + boff0);
        bR[i][1] = has1 ? *reinterpret_cast<const bf16x8*>(BtgC + kt * 3584 + boff1)
                        : (bf16x8)0;
    }
}

// load A-frags (both essays, 4 m-tiles) for conv k-tile KT
template<int KT>
__device__ __forceinline__ void conv_loadA(
    const unsigned short* b0p, const unsigned short* b1p,
    const int (&abase)[MTILES], bf16x8 (&a)[2][MTILES])
{
    constexpr int w   = KT / 10;
    constexpr int t   = KT % 10;
    constexpr int off = w * PX + t * 32;
#pragma unroll
    for (int mt = 0; mt < MTILES; ++mt) {
        a[0][mt] = *reinterpret_cast<const bf16x8*>(&b0p[abase[mt] + off]);
        a[1][mt] = *reinterpret_cast<const bf16x8*>(&b1p[abase[mt] + off]);
    }
}

__device__ __forceinline__ void mfma16(
    const bf16x8 (&a)[2][MTILES], const bf16x8 (&b)[2], bool has1,
    f32x4 (&acc)[2][MTILES][2])
{
    __builtin_amdgcn_s_setprio(1);
#pragma unroll
    for (int es = 0; es < 2; ++es) {
#pragma unroll
        for (int mt = 0; mt < MTILES; ++mt) {
            acc[es][mt][0] = __builtin_amdgcn_mfma_f32_16x16x32_bf16(a[es][mt], b[0], acc[es][mt][0], 0, 0, 0);
            if (has1)
                acc[es][mt][1] = __builtin_amdgcn_mfma_f32_16x16x32_bf16(a[es][mt], b[1], acc[es][mt][1], 0, 0, 0);
        }
    }
    __builtin_amdgcn_s_setprio(0);
}

// one conv k-tile: prefetch A for KT+1 into the other buffer, then 16 MFMAs
template<int KT>
__device__ __forceinline__ void conv_kt(
    const unsigned short* b0p, const unsigned short* b1p,
    const int (&abase)[MTILES], bool has1, const bf16x8 (&b)[2],
    bf16x8 (&aX)[2][MTILES], bf16x8 (&aY)[2][MTILES],
    f32x4 (&acc)[2][MTILES][2])
{
    constexpr bool even = (KT % 2) == 0;
    if constexpr (KT + 1 < KT_CONV) {
        if constexpr (even) conv_loadA<KT + 1>(b0p, b1p, abase, aY);
        else                conv_loadA<KT + 1>(b0p, b1p, abase, aX);
    }
    if constexpr (even) mfma16(aX, b, has1, acc);
    else                mfma16(aY, b, has1, acc);
}

template<int G>
__device__ __forceinline__ void conv_group(
    const unsigned short* b0p, const unsigned short* b1p,
    const int (&abase)[MTILES], bool has1, const bf16x8 (&bR)[5][2],
    bf16x8 (&aX)[2][MTILES], bf16x8 (&aY)[2][MTILES],
    f32x4 (&acc)[2][MTILES][2])
{
    conv_kt<G * 5 + 0>(b0p, b1p, abase, has1, bR[0], aX, aY, acc);
    conv_kt<G * 5 + 1>(b0p, b1p, abase, has1, bR[1], aX, aY, acc);
    conv_kt<G * 5 + 2>(b0p, b1p, abase, has1, bR[2], aX, aY, acc);
    conv_kt<G * 5 + 3>(b0p, b1p, abase, has1, bR[3], aX, aY, acc);
    conv_kt<G * 5 + 4>(b0p, b1p, abase, has1, bR[4], aX, aY, acc);
}

// att1 A-frag load for k-tile KT (convbf layout, pitch PC)
template<int KT>
__device__ __forceinline__ void att_loadA(
    const unsigned short* b0p, const unsigned short* b1p,
    const int (&abase2)[MTILES], bf16x8 (&a)[2][MTILES])
{
    constexpr int off = KT * 32;
#pragma unroll
    for (int mt = 0; mt < MTILES; ++mt) {
        a[0][mt] = *reinterpret_cast<const bf16x8*>(&b0p[abase2[mt] + off]);
        a[1][mt] = *reinterpret_cast<const bf16x8*>(&b1p[abase2[mt] + off]);
    }
}

// ---------------------------------------------------------------------------
// Kernel 1: TWO essays per block. conv via bf16 MFMA + att1 pooling.
// grid = B*E/2 blocks, 256 threads (4 waves). Waves split N-tiles.
// ---------------------------------------------------------------------------
__global__ __launch_bounds__(256, 2) void conv_att1_kernel(
    const float* __restrict__ essays,       // [B,E,S,D]
    const unsigned short* __restrict__ BtgC,// [50][112][32] bf16
    const unsigned short* __restrict__ BtgA,// [4][112][32] bf16
    const float* __restrict__ conv_b,       // [F]
    const float* __restrict__ att1_bias,    // [F]
    const float* __restrict__ att1_vec,     // [F]
    unsigned short* __restrict__ sent_bf)   // [2048][128] bf16 (cols 100..127 = 0)
{
    __shared__ __align__(16) unsigned short buf[2][54 * PX];   // 70848 B
    __shared__ float u_s[2][64];
    __shared__ float alpha_s[2][64];

    const int be0 = blockIdx.x * 2;
    const int tid = threadIdx.x;
    const int lane = tid & 63;
    const int wid  = tid >> 6;           // 0..3
    const int ln   = lane & 15;
    const int qd   = lane >> 4;          // 0..3

    if (tid < 128) u_s[tid >> 6][tid & 63] = 0.f;

    // wave n-tile assignment + offsets (needed before barrier for B prefetch)
    const int nt0 = wid;
    const int nt1 = wid + 4;
    const bool has1 = (nt1 < NTILES);
    const int boff0 = (nt0 * 16 + ln) * 32 + 8 * qd;
    const int boff1 = (nt1 * 16 + ln) * 32 + 8 * qd;

    int abase[MTILES];
#pragma unroll
    for (int mt = 0; mt < MTILES; ++mt) {
        const int m = mt * 16 + ln;
        abase[mt] = (m < Ssz ? m : Ssz - 1) * PX + 8 * qd;
    }

    // issue first two B groups NOW: L2 latency hides under staging + barrier
    bf16x8 bX[5][2], bY[5][2];
    conv_loadB<0>(BtgC, boff0, boff1, has1, bX);
    conv_loadB<1>(BtgC, boff0, boff1, has1, bY);

    // ---- stage Xp for both essays (bf16, zero-padded) ----
#pragma unroll
    for (int es = 0; es < 2; ++es) {
        const float* in_g = essays + (size_t)(be0 + es) * (Ssz * Dsz);
        float4 va[9], vb[9];
        int rr[9], cc[9];
        bool hv[9], fv[9], gv[9];
#pragma unroll
        for (int it = 0; it < 9; ++it) {
            const int g  = tid + it * 256;
            const int r  = g / 41;
            const int c8 = (g - r * 41) * 8;
            const int s  = r - 2;
            gv[it] = (g < NGRP);
            hv[it] = gv[it] && (s >= 0) && (s < Ssz) && (c8 < Dsz);
            fv[it] = hv[it] && (c8 + 8 <= Dsz);
            const float* base = in_g + (hv[it] ? (s * Dsz + c8) : 0);
            va[it] = *reinterpret_cast<const float4*>(base);
            vb[it] = *reinterpret_cast<const float4*>(fv[it] ? base + 4 : base);
            rr[it] = r; cc[it] = c8;
        }
#pragma unroll
        for (int it = 0; it < 9; ++it) {
            if (!gv[it]) continue;
            const float e0 = hv[it] ? va[it].x : 0.f;
            const float e1 = hv[it] ? va[it].y : 0.f;
            const float e2 = hv[it] ? va[it].z : 0.f;
            const float e3 = hv[it] ? va[it].w : 0.f;
            const float e4 = fv[it] ? vb[it].x : 0.f;
            const float e5 = fv[it] ? vb[it].y : 0.f;
            const float e6 = fv[it] ? vb[it].z : 0.f;
            const float e7 = fv[it] ? vb[it].w : 0.f;
            uint4 o;
            o.x = f2bf2(e0, e1);
            o.y = f2bf2(e2, e3);
            o.z = f2bf2(e4, e5);
            o.w = f2bf2(e6, e7);
            *reinterpret_cast<uint4*>(&buf[es][rr[it] * PX + cc[it]]) = o;
        }
    }
    __syncthreads();

    // ---- conv MFMA: M=2x64, N=112, K'=1600, A-prefetch pipelined ----
    const unsigned short* b0p = buf[0];
    const unsigned short* b1p = buf[1];

    f32x4 acc[2][MTILES][2];
#pragma unroll
    for (int es = 0; es < 2; ++es)
#pragma unroll
        for (int mt = 0; mt < MTILES; ++mt) { acc[es][mt][0] = (f32x4)0.f; acc[es][mt][1] = (f32x4)0.f; }

    {
        bf16x8 aX[2][MTILES], aY[2][MTILES];
        conv_loadA<0>(b0p, b1p, abase, aX);
        conv_group<0>(b0p, b1p, abase, has1, bX, aX, aY, acc);
        conv_loadB<2>(BtgC, boff0, boff1, has1, bX);
        conv_group<1>(b0p, b1p, abase, has1, bY, aX, aY, acc);
        conv_loadB<3>(BtgC, boff0, boff1, has1, bY);
        conv_group<2>(b0p, b1p, abase, has1, bX, aX, aY, acc);
        conv_loadB<4>(BtgC, boff0, boff1, has1, bX);
        conv_group<3>(b0p, b1p, abase, has1, bY, aX, aY, acc);
        conv_loadB<5>(BtgC, boff0, boff1, has1, bY);
        conv_group<4>(b0p, b1p, abase, has1, bX, aX, aY, acc);
        conv_loadB<6>(BtgC, boff0, boff1, has1, bX);
        conv_group<5>(b0p, b1p, abase, has1, bY, aX, aY, acc);
        conv_loadB<7>(BtgC, boff0, boff1, has1, bY);
        conv_group<6>(b0p, b1p, abase, has1, bX, aX, aY, acc);
        conv_loadB<8>(BtgC, boff0, boff1, has1, bX);
        conv_group<7>(b0p, b1p, abase, has1, bY, aX, aY, acc);
        conv_loadB<9>(BtgC, boff0, boff1, has1, bY);
        conv_group<8>(b0p, b1p, abase, has1, bX, aX, aY, acc);
        conv_group<9>(b0p, b1p, abase, has1, bY, aX, aY, acc);
    }

    // issue att1 B loads early (global, independent of LDS overlay)
    bf16x8 a1b[4][2];
#pragma unroll
    for (int kt = 0; kt < 4; ++kt) {
        a1b[kt][0] = *reinterpret_cast<const bf16x8*>(BtgA + kt * 3584 + boff0);
        a1b[kt][1] = has1 ? *reinterpret_cast<const bf16x8*>(BtgA + kt * 3584 + boff1)
                          : (bf16x8)0;
    }
    __syncthreads();   // Xp dead from here; convbf overlays buf

    // ---- epilogue: bias + relu -> convbf (bf16, overlaid at buf[es]) ----
    {
        const float bias0 = conv_b[nt0 * 16 + ln];    // nt0*16+ln < 100 always
        const int n_g1 = nt1 * 16 + ln;
        const bool g1ok = has1 && (n_g1 < Fsz);
        const float bias1 = g1ok ? conv_b[n_g1] : 0.f;
#pragma unroll
        for (int es = 0; es < 2; ++es) {
#pragma unroll
            for (int mt = 0; mt < MTILES; ++mt) {
#pragma unroll
                for (int j = 0; j < 4; ++j) {
                    const int m_row = mt * 16 + qd * 4 + j;
                    buf[es][m_row * PC + nt0 * 16 + ln] = f2bf(fmaxf(acc[es][mt][0][j] + bias0, 0.f));
                    if (g1ok)
                        buf[es][m_row * PC + n_g1] = f2bf(fmaxf(acc[es][mt][1][j] + bias1, 0.f));
                }
            }
        }
    }
    // zero K-pad cols 112..127 of convbf (att1 MFMA reads K up to 128)
    for (int idx = tid; idx < 2 * 64 * 2; idx += 256) {
        const int es = idx >> 7;
        const int r2 = idx & 127;
        const int row = r2 >> 1;
        const int c = 112 + (r2 & 1) * 8;
        *reinterpret_cast<u16x8*>(&buf[es][row * PC + c]) = (u16x8)0;
    }
    __syncthreads();

    // ---- att1 scores MFMA (A-prefetch pipelined) ----
    f32x4 acc2[2][MTILES][2];
#pragma unroll
    for (int es = 0; es < 2; ++es)
#pragma unroll
        for (int mt = 0; mt < MTILES; ++mt) { acc2[es][mt][0] = (f32x4)0.f; acc2[es][mt][1] = (f32x4)0.f; }

    {
        int abase2[MTILES];
#pragma unroll
        for (int mt = 0; mt < MTILES; ++mt) abase2[mt] = (mt * 16 + ln) * PC + 8 * qd;

        bf16x8 aX[2][MTILES], aY[2][MTILES];
        att_loadA<0>(b0p, b1p, abase2, aX);
        att_loadA<1>(b0p, b1p, abase2, aY);
        mfma16(aX, a1b[0], has1, acc2);
        att_loadA<2>(b0p, b1p, abase2, aX);
        mfma16(aY, a1b[1], has1, acc2);
        att_loadA<3>(b0p, b1p, abase2, aY);
        mfma16(aX, a1b[2], has1, acc2);
        mfma16(aY, a1b[3], has1, acc2);
    }

    // scores: tanh(acc2+bias)*vec; combine both n-tiles, reduce 16 ln-lanes, atomic
    {
        const int g0 = nt0 * 16 + ln;                 // always < 100
        const float b1v0 = att1_bias[g0];
        const float vv0  = att1_vec[g0];
        const int g1 = nt1 * 16 + ln;
        const bool g1v = has1 && (g1 < Fsz);
        const float b1v1 = g1v ? att1_bias[g1] : 0.f;
        const float vv1  = g1v ? att1_vec[g1]  : 0.f;
#pragma unroll
        for (int es = 0; es < 2; ++es) {
#pragma unroll
            for (int mt = 0; mt < MTILES; ++mt) {
#pragma unroll
                for (int j = 0; j < 4; ++j) {
                    const int m_row = mt * 16 + qd * 4 + j;
                    float val = 0.f;
                    if (m_row < Ssz) {
                        val = tanhf_fast(acc2[es][mt][0][j] + b1v0) * vv0;
                        if (g1v) val += tanhf_fast(acc2[es][mt][1][j] + b1v1) * vv1;
                    }
                    val += __shfl_xor(val, 1);
                    val += __shfl_xor(val, 2);
                    val += __shfl_xor(val, 4);
                    val += __shfl_xor(val, 8);
                    if (ln == 0 && m_row < Ssz) atomicAdd(&u_s[es][m_row], val);
                }
            }
        }
    }
    __syncthreads();

    // ---- softmax over s (waves 0 and 1, one essay each) ----
    if (wid < 2) {
        const float uv = (lane < Ssz) ? u_s[wid][lane] : -1e30f;
        float m = uv;
#pragma unroll
        for (int off = 32; off > 0; off >>= 1) m = fmaxf(m, __shfl_xor(m, off));
        float e = (lane < Ssz) ? __expf(uv - m) : 0.f;
        float sum = e;
#pragma unroll
        for (int off = 32; off > 0; off >>= 1) sum += __shfl_xor(sum, off);
        alpha_s[wid][lane] = e / sum;
    }
    __syncthreads();

    // ---- sent_bf: all 256 threads (es = tid>>7, col = tid&127) ----
    {
        const int es = tid >> 7;
        const int f  = tid & 127;
        unsigned short v = 0;
        if (f < Fsz) {
            float a = 0.f;
            for (int s = 0; s < Ssz; ++s) a += alpha_s[es][s] * bf2f(buf[es][s * PC + f]);
            v = f2bf(a);
        }
        sent_bf[(size_t)(be0 + es) * 128 + f] = v;
    }
}

// ---------------------------------------------------------------------------
// Kernel 1b: xpart = sent_bf @ Wx + lstm_b  -> [2048][400] fp32
// grid = 32 blocks x 256 threads; wave w handles M-tile blockIdx*4+w
// ---------------------------------------------------------------------------
__global__ __launch_bounds__(256) void xpart_kernel(
    const unsigned short* __restrict__ sent_bf, // [2048][128]
    const unsigned short* __restrict__ BtgW,    // [4][400][32]
    const float* __restrict__ lstm_b,           // [400]
    float* __restrict__ xpart)                  // [2048][400]
{
    const int wid  = threadIdx.x >> 6;
    const int mt   = blockIdx.x * 4 + wid;      // 0..127
    const int lane = threadIdx.x & 63;
    const int ln   = lane & 15;
    const int qd   = lane >> 4;
    const int m0   = mt * 16;

    f32x4 acc[25];
#pragma unroll
    for (int nt = 0; nt < 25; ++nt) acc[nt] = (f32x4)0.f;

#pragma unroll
    for (int kt = 0; kt < 4; ++kt) {
        const bf16x8 a = *reinterpret_cast<const bf16x8*>(
            sent_bf + (size_t)(m0 + ln) * 128 + kt * 32 + 8 * qd);
#pragma unroll
        for (int nt = 0; nt < 25; ++nt) {
            const bf16x8 b = *reinterpret_cast<const bf16x8*>(
                BtgW + ((size_t)kt * 400 + nt * 16 + ln) * 32 + 8 * qd);
            acc[nt] = __builtin_amdgcn_mfma_f32_16x16x32_bf16(a, b, acc[nt], 0, 0, 0);
        }
    }

#pragma unroll
    for (int nt = 0; nt < 25; ++nt) {
        const int col = nt * 16 + ln;
        const float bias = lstm_b[col];
#pragma unroll
        for (int j = 0; j < 4; ++j) {
            const int row = m0 + qd * 4 + j;
            xpart[(size_t)row * 400 + col] = acc[nt][j] + bias;
        }
    }
}

// ---------------------------------------------------------------------------
// Kernel 2: LSTM recurrence + att2 pooling + dense, fused per batch row.
// grid = B blocks, 448 threads (400 active in recurrence).
// ---------------------------------------------------------------------------
__global__ __launch_bounds__(448) void lstm_att2_kernel(
    const float* __restrict__ xpart,     // [2048][400] (bias included)
    const float* __restrict__ lstm_W,    // [200][400]
    const float* __restrict__ att2_mat,  // [H,H]
    const float* __restrict__ att2_bias, // [H]
    const float* __restrict__ att2_vec,  // [H]
    const float* __restrict__ dense_w,   // [H]
    const float* __restrict__ dense_b,   // [1]
    float* __restrict__ out)             // [B]
{
    __shared__ __align__(16) float h_s[Hsz];
    __shared__ float z_s[400];
    __shared__ __align__(16) float hist[Esz][Hsz];   // 25.6 KB
    __shared__ float w2_s[Esz * Hsz];                // 25.6 KB
    __shared__ float u2_s[Esz];
    __shared__ float alpha2_s[Esz];
    __shared__ float repr_s[Hsz];

    const int b = blockIdx.x;
    const int tid = threadIdx.x;
    const bool actv = tid < 400;

    float w[100];
    if (actv) {
#pragma unroll
        for (int k = 0; k < 100; ++k) w[k] = lstm_W[(size_t)(Fsz + k) * 400 + tid];
    }
    float c = 0.f;
    if (tid < Hsz) h_s[tid] = 0.f;
    __syncthreads();

    float xp_cur = actv ? xpart[(size_t)b * Esz * 400 + tid] : 0.f;
    const float4* h4 = reinterpret_cast<const float4*>(h_s);

    for (int t = 0; t < Esz; ++t) {
        const float xp_next = (actv && (t + 1) < Esz)
            ? xpart[((size_t)b * Esz + t + 1) * 400 + tid] : 0.f;
        if (actv) {
            float z0 = xp_cur, z1 = 0.f, z2 = 0.f, z3 = 0.f;
#pragma unroll
            for (int k4 = 0; k4 < 25; ++k4) {
                const float4 hv = h4[k4];
                z0 += hv.x * w[4 * k4 + 0];
                z1 += hv.y * w[4 * k4 + 1];
                z2 += hv.z * w[4 * k4 + 2];
                z3 += hv.w * w[4 * k4 + 3];
            }
            z_s[tid] = (z0 + z1) + (z2 + z3);
        }
        __syncthreads();

        if (tid < Hsz) {
            const float zi = z_s[tid];
            const float zj = z_s[tid + 100];
            const float zf = z_s[tid + 200];
            const float zo = z_s[tid + 300];
            c = c * sigmoid_fast(zf + 1.0f) + sigmoid_fast(zi) * tanhf_fast(zj);
            const float h = sigmoid_fast(zo) * tanhf_fast(c);
            h_s[tid] = h;
            hist[t][tid] = h;
        }
        __syncthreads();
        xp_cur = xp_next;
    }

    // ---- att2 on hist ----
    for (int idx = tid; idx < Esz * Hsz; idx += 448) {
        const int e = idx / Hsz;
        const int g = idx - e * Hsz;
        const float* lp = hist[e];
        float a0 = 0.f, a1 = 0.f, a2 = 0.f, a3 = 0.f;
        for (int k = 0; k < Hsz; k += 4) {
            a0 += lp[k + 0] * att2_mat[(k + 0) * Hsz + g];
            a1 += lp[k + 1] * att2_mat[(k + 1) * Hsz + g];
            a2 += lp[k + 2] * att2_mat[(k + 2) * Hsz + g];
            a3 += lp[k + 3] * att2_mat[(k + 3) * Hsz + g];
        }
        w2_s[idx] = tanhf_fast(att2_bias[g] + ((a0 + a1) + (a2 + a3))) * att2_vec[g];
    }
    __syncthreads();

    if (tid < Esz) {
        float acc = 0.f;
        const float* wp = w2_s + tid * Hsz;
        for (int g = 0; g < Hsz; ++g) acc += wp[g];
        u2_s[tid] = acc;
    }
    __syncthreads();

    if (tid < 64) {
        const float uv = u2_s[tid];
        float m = uv;
#pragma unroll
        for (int off = 32; off > 0; off >>= 1) m = fmaxf(m, __shfl_xor(m, off));
        float e = __expf(uv - m);
        float sum = e;
#pragma unroll
        for (int off = 32; off > 0; off >>= 1) sum += __shfl_xor(sum, off);
        alpha2_s[tid] = e / sum;
    }
    __syncthreads();

    if (tid < Hsz) {
        float acc = 0.f;
        for (int e = 0; e < Esz; ++e) acc += alpha2_s[e] * hist[e][tid];
        repr_s[tid] = acc;
    }
    __syncthreads();

    if (tid == 0) {
        float acc = dense_b[0];
        for (int hh = 0; hh < Hsz; ++hh) acc += repr_s[hh] * dense_w[hh];
        out[b] = sigmoid_fast(acc);
    }
}

// ---------------------------------------------------------------------------
extern "C" void kernel_launch(void* const* d_in, const int* in_sizes, int n_in,
                              void* d_out, int out_size, void* d_ws, size_t ws_size,
                              hipStream_t stream) {
    const float* essays    = (const float*)d_in[0];
    const float* conv_k    = (const float*)d_in[1];
    const float* conv_b    = (const float*)d_in[2];
    const float* att1_mat  = (const float*)d_in[3];
    const float* att1_bias = (const float*)d_in[4];
    const float* att1_vec  = (const float*)d_in[5];
    const float* lstm_W    = (const float*)d_in[6];
    const float* lstm_b    = (const float*)d_in[7];
    const float* att2_mat  = (const float*)d_in[8];
    const float* att2_bias = (const float*)d_in[9];
    const float* att2_vec  = (const float*)d_in[10];
    const float* dense_w   = (const float*)d_in[11];
    const float* dense_b   = (const float*)d_in[12];

    float* out = (float*)d_out;

    // workspace layout (256B-aligned chunks)
    char* ws = (char*)d_ws;
    unsigned short* sent_bf = (unsigned short*)ws;              // 524288 B
    float* xpart = (float*)(ws + 524288);                       // 3276800 B
    unsigned short* BtgC = (unsigned short*)(ws + 3801088);     // 358400 B
    unsigned short* BtgA = (unsigned short*)(ws + 4159488);     // 28672 B
    unsigned short* BtgW = (unsigned short*)(ws + 4188160);     // 102400 B

    prep_kernel<<<512, 256, 0, stream>>>(conv_k, att1_mat, lstm_W, BtgC, BtgA, BtgW);
    conv_att1_kernel<<<Bsz * Esz / 2, 256, 0, stream>>>(
        essays, BtgC, BtgA, conv_b, att1_bias, att1_vec, sent_bf);
    xpart_kernel<<<32, 256, 0, stream>>>(sent_bf, BtgW, lstm_b, xpart);
    lstm_att2_kernel<<<Bsz, 448, 0, stream>>>(
        xpart, lstm_W, att2_mat, att2_bias, att2_vec, dense_w, dense_b, out);
}